// Round 9
// baseline (104632.617 us; speedup 1.0000x reference)
//
#include <hip/hip_runtime.h>
#include <math.h>

#define NPTS   2048
#define DIM    96
#define PITCH  2048
#define TB     8
#define ROUNDS 8      // expected a after 8 MNN rounds: 2048*0.69^8 ~ 105 <= TAILSZ
#define TAILSZ 160
#define TPAD   162
#define FNTHR  512

// ---- fixed-slot state: slot index == cluster representative (min point) ----
__device__ double g_cent[DIM * PITCH];   // transposed centroids, in-place updates
__device__ double g_sz[NPTS];
__device__ double g_nrm[NPTS];           // ||mu||^2
__device__ int    g_act[NPTS];
__device__ int    g_cidx[NPTS];          // compacted active slot ids, ascending
__device__ double g_nnv[NPTS];
__device__ int    g_nni[NPTS];           // -1 for killed slots
__device__ int    g_reci[NPTS];          // merge records: keeper (smaller slot)
__device__ int    g_recj[NPTS];          //                killed (larger slot)
__device__ double g_rech[NPTS];          //                Ward height
__device__ int    g_a, g_done, g_mcount;

// ---------------------------------------------------------------- init ----
__global__ void init_kernel(const float* __restrict__ x) {
    int p = blockIdx.x * 256 + threadIdx.x;   // grid 8 x 256
    if (p < NPTS) {
        double nr = 0.0;
        for (int d = 0; d < DIM; ++d) {
            double v = (double)x[p * DIM + d];
            g_cent[d * PITCH + p] = v;
            nr += v * v;
        }
        g_nrm[p] = nr; g_sz[p] = 1.0; g_act[p] = 1; g_cidx[p] = p;
        g_nni[p] = -1; g_nnv[p] = (double)INFINITY;
    }
    if (p == 0) { g_a = NPTS; g_done = 0; g_mcount = 0; }
}

// -------------------------------------------------------------- nn_pass ----
// (verbatim from the R6-passing kernel)
__global__ void __launch_bounds__(512) nn_pass() {
    if (g_done) return;
    const int a = g_a;
    const int tile0 = blockIdx.x * TB;
    if (tile0 >= a) return;
    const int t = threadIdx.x;

    __shared__ int    sIdx[TB];
    __shared__ double sMu[DIM * TB];
    __shared__ double sNb[TB], sSb[TB];
    __shared__ double sRedV[8 * TB];
    __shared__ int    sRedI[8 * TB];

    if (t < TB) {
        int cm   = tile0 + t;
        int orig = (cm < a) ? g_cidx[cm] : -1;
        sIdx[t] = orig;
        sNb[t]  = (orig >= 0) ? g_nrm[orig] : 0.0;
        sSb[t]  = (orig >= 0) ? g_sz[orig]  : 1.0;
    }
    __syncthreads();
    for (int e = t; e < DIM * TB; e += 512) {
        int col = sIdx[e & 7];
        sMu[e] = (col >= 0) ? g_cent[(e >> 3) * PITCH + col] : 0.0;
    }
    __syncthreads();

    int om[4]; bool vld[4];
#pragma unroll
    for (int q = 0; q < 4; ++q) {
        int m  = t + q * 512;
        vld[q] = (m < a);
        om[q]  = g_cidx[vld[q] ? m : (a - 1)];
    }
    double acc[4][TB];
#pragma unroll
    for (int q = 0; q < 4; ++q)
#pragma unroll
        for (int bi = 0; bi < TB; ++bi) acc[q][bi] = 0.0;

    for (int d = 0; d < DIM; ++d) {
        double mu[TB];
#pragma unroll
        for (int bi = 0; bi < TB; ++bi) mu[bi] = sMu[d * TB + bi];
        double x0 = g_cent[d * PITCH + om[0]];
        double x1 = g_cent[d * PITCH + om[1]];
        double x2 = g_cent[d * PITCH + om[2]];
        double x3 = g_cent[d * PITCH + om[3]];
#pragma unroll
        for (int bi = 0; bi < TB; ++bi) {
            acc[0][bi] += mu[bi] * x0;
            acc[1][bi] += mu[bi] * x1;
            acc[2][bi] += mu[bi] * x2;
            acc[3][bi] += mu[bi] * x3;
        }
    }

    double bv[TB]; int bidx[TB];
#pragma unroll
    for (int bi = 0; bi < TB; ++bi) { bv[bi] = (double)INFINITY; bidx[bi] = 0x7FFFFFFF; }
#pragma unroll
    for (int q = 0; q < 4; ++q) {
        if (!vld[q]) continue;
        int    cm = t + q * 512;
        double sm = g_sz[om[q]], nm = g_nrm[om[q]];
#pragma unroll
        for (int bi = 0; bi < TB; ++bi) {
            double f = (sSb[bi] * sm) / (sSb[bi] + sm);
            double D = (2.0 * f) * ((sNb[bi] + nm) - 2.0 * acc[q][bi]);
            if (cm != tile0 + bi && D < bv[bi]) { bv[bi] = D; bidx[bi] = om[q]; }
        }
    }

    const int lane = t & 63, w = t >> 6;
#pragma unroll
    for (int bi = 0; bi < TB; ++bi) {
        double v = bv[bi]; int ix = bidx[bi];
        for (int off = 1; off < 64; off <<= 1) {
            double ov = __shfl_xor(v, off);
            int    oi = __shfl_xor(ix, off);
            if (ov < v || (ov == v && oi < ix)) { v = ov; ix = oi; }
        }
        if (lane == 0) { sRedV[w * TB + bi] = v; sRedI[w * TB + bi] = ix; }
    }
    __syncthreads();
    if (t < TB && tile0 + t < a) {
        double v = sRedV[t]; int ix = sRedI[t];
        for (int w2 = 1; w2 < 8; ++w2) {
            double ov = sRedV[w2 * TB + t]; int oi = sRedI[w2 * TB + t];
            if (ov < v || (ov == v && oi < ix)) { v = ov; ix = oi; }
        }
        g_nnv[sIdx[t]] = v;
        g_nni[sIdx[t]] = ix;
    }
}

// ----------------------------------------------------------- merge_pass ----
// (verbatim R6, except stop condition a2 <= TAILSZ)
__global__ void __launch_bounds__(1024) merge_pass() {
    if (g_done) return;
    __shared__ int sWave[16];
    const int t = threadIdx.x, lane = t & 63, w = t >> 6;

    for (int b = t; b < NPTS; b += 1024) {
        int j = g_nni[b];
        if (j > b && j < NPTS && g_nni[j] == b) {   // mutual pair, b = keeper
            int r = atomicAdd(&g_mcount, 1);
            g_reci[r] = b; g_recj[r] = j; g_rech[r] = g_nnv[b];
            double sb = g_sz[b], sj = g_sz[j], s2 = sb + sj;
            double nr = 0.0;
            for (int d = 0; d < DIM; ++d) {
                double v = (sb * g_cent[d * PITCH + b] + sj * g_cent[d * PITCH + j]) / s2;
                g_cent[d * PITCH + b] = v;
                nr += v * v;
            }
            g_sz[b] = s2; g_nrm[b] = nr;
            g_act[j] = 0; g_nni[j] = -1; g_nnv[j] = (double)INFINITY;
        }
    }
    __syncthreads();

    int e0 = 2 * t, e1 = 2 * t + 1;
    int c0 = g_act[e0], c1 = g_act[e1];
    int sum = c0 + c1;
    int v = sum;
    for (int off = 1; off < 64; off <<= 1) {
        int o = __shfl_up(v, off);
        if (lane >= off) v += o;
    }
    if (lane == 63) sWave[w] = v;
    __syncthreads();
    if (t == 0) {
        int run = 0;
        for (int i = 0; i < 16; ++i) { int x = sWave[i]; sWave[i] = run; run += x; }
    }
    __syncthreads();
    int base = sWave[w] + (v - sum);
    if (c0) g_cidx[base]      = e0;
    if (c1) g_cidx[base + c0] = e1;
    if (t == 1023) {
        int a2 = base + sum;
        g_a = a2;
        g_done = (a2 <= TAILSZ) ? 1 : 0;
    }
}

// Per-block order-preserving compaction of g_act -> sCidx (512 threads).
__device__ __forceinline__ int block_compact(unsigned short* sCidx, int* sWS) {
    const int t = threadIdx.x, lane = t & 63, w = t >> 6;
    int base = t * 4;
    int c0 = g_act[base], c1 = g_act[base + 1], c2 = g_act[base + 2], c3 = g_act[base + 3];
    int sum = c0 + c1 + c2 + c3;
    int v = sum;
#pragma unroll
    for (int off = 1; off < 64; off <<= 1) {
        int o = __shfl_up(v, off);
        if (lane >= off) v += o;
    }
    if (lane == 63) sWS[w] = v;
    __syncthreads();
    if (t == 0) {
        int run = 0;
#pragma unroll
        for (int i = 0; i < 8; ++i) { int x = sWS[i]; sWS[i] = run; run += x; }
        sWS[8] = run;
    }
    __syncthreads();
    int ex = sWS[w] + (v - sum);
    if (c0) sCidx[ex] = (unsigned short)base;       ex += c0;
    if (c1) sCidx[ex] = (unsigned short)(base + 1); ex += c1;
    if (c2) sCidx[ex] = (unsigned short)(base + 2); ex += c2;
    if (c3) sCidx[ex] = (unsigned short)(base + 3); ex += c3;
    int a = sWS[8];
    __syncthreads();
    return a;
}

// ------------------------------------------------------------- finisher ----
// A: (rare) global-mem MNN rounds over COMPACTED rows while a > TAILSZ.
// B: LDS-resident tail (R8-proven) from a <= 160 down to a == 1.
// C: phase-3 (R5/R8-proven): sort heights, cut n-k, union-find, rank, scatter.
__global__ void __launch_bounds__(FNTHR) finisher(const int* __restrict__ kptr,
                                                  float* __restrict__ out, int out_size) {
    __shared__ unsigned short sCidx[NPTS];     //   4 KB
    __shared__ int    sWS[16];
    __shared__ int    sNp;
    __shared__ double tCent[DIM * TPAD];       // 124.4 KB arena (A/B/C overlays)
    __shared__ double tSz[TAILSZ], tNr[TAILSZ], tNNv[TAILSZ];
    __shared__ int    tNNi[TAILSZ], tCid[TAILSZ];
    __shared__ unsigned char tAct[TAILSZ];

    const int t = threadIdx.x, lane = t & 63, w = t >> 6;
    const int k = *kptr;

    // zero output (replaces the memset node; harness does not re-poison)
    for (int i = t; i < out_size; i += FNTHR) out[i] = 0.0f;

    int a = block_compact(sCidx, sWS);

    // ---- phase A: fallback global-mem MNN rounds (normally skipped) ----
    {
        double* aD0 = tCent;                     // by compacted position
        int*    aI0 = (int*)(tCent + 2048);
        while (a > TAILSZ) {
            for (int c = w; c < a; c += 8) {     // wave per compacted row
                int b = (int)sCidx[c];
                double sb = g_sz[b], nb = g_nrm[b];
                double bv = (double)INFINITY; int bi = 0x7FFFFFFF;
                for (int cm = lane; cm < a; cm += 64) {
                    int m = (int)sCidx[cm];
                    if (m == b) continue;
                    double dot = 0.0;
                    for (int d = 0; d < DIM; ++d)
                        dot += g_cent[d * PITCH + b] * g_cent[d * PITCH + m];
                    double sm = g_sz[m];
                    double f = (sb * sm) / (sb + sm);
                    double D = (2.0 * f) * ((nb + g_nrm[m]) - 2.0 * dot);
                    if (D < bv) { bv = D; bi = cm; }   // ascending cm: smallest pos tie
                }
#pragma unroll
                for (int off = 1; off < 64; off <<= 1) {
                    double ov = __shfl_xor(bv, off);
                    int    oi = __shfl_xor(bi, off);
                    if (ov < bv || (ov == bv && oi < bi)) { bv = ov; bi = oi; }
                }
                if (lane == 0) { aD0[c] = bv; aI0[c] = bi; }
            }
            __syncthreads();
            if (t == 0) sNp = 0;
            __syncthreads();
            for (int c = t; c < a; c += FNTHR) {
                int jc = aI0[c];
                if (jc > c && jc < a && aI0[jc] == c) {   // mutual by position
                    int b = (int)sCidx[c], j = (int)sCidx[jc];
                    double sb = g_sz[b], sj = g_sz[j], s2 = sb + sj;
                    double nr = 0.0;
                    for (int d = 0; d < DIM; ++d) {
                        double v = (sb * g_cent[d * PITCH + b] + sj * g_cent[d * PITCH + j]) / s2;
                        g_cent[d * PITCH + b] = v; nr += v * v;
                    }
                    g_sz[b] = s2; g_nrm[b] = nr; g_act[j] = 0;
                    int r = atomicAdd(&g_mcount, 1);
                    g_reci[r] = b; g_recj[r] = j; g_rech[r] = aD0[c];
                    atomicAdd(&sNp, 1);
                }
            }
            __syncthreads();
            a = block_compact(sCidx, sWS);
        }
    }

    // ---- phase B: LDS-resident tail to full dendrogram (R8-proven) ----
    const int a0 = a;
    for (int p = t; p < TAILSZ; p += FNTHR) {
        bool vv = (p < a0);
        int orig = vv ? (int)sCidx[p] : 0;
        for (int d = 0; d < DIM; ++d)
            tCent[d * TPAD + p] = vv ? g_cent[d * PITCH + orig] : 0.0;
        tSz[p]  = vv ? g_sz[orig]  : 1.0;
        tNr[p]  = vv ? g_nrm[orig] : 0.0;
        tCid[p] = orig;
        tAct[p] = vv ? 1 : 0;
    }
    __syncthreads();

    while (a > 1) {
        if (t < TAILSZ && tAct[t]) {
            double sb = tSz[t], nb = tNr[t];
            double bv = (double)INFINITY; int bi = 0x7FFFFFFF;
            for (int m = 0; m < TAILSZ; ++m) {
                if (!tAct[m]) continue;
                double d0 = 0.0, d1 = 0.0, d2 = 0.0, d3 = 0.0;
#pragma unroll
                for (int d = 0; d < DIM; d += 4) {      // 4-way split, bit-symmetric
                    d0 += tCent[(d    ) * TPAD + t] * tCent[(d    ) * TPAD + m];
                    d1 += tCent[(d + 1) * TPAD + t] * tCent[(d + 1) * TPAD + m];
                    d2 += tCent[(d + 2) * TPAD + t] * tCent[(d + 2) * TPAD + m];
                    d3 += tCent[(d + 3) * TPAD + t] * tCent[(d + 3) * TPAD + m];
                }
                double dot = (d0 + d1) + (d2 + d3);
                double sm = tSz[m];
                double f = (sb * sm) / (sb + sm);
                double D = (2.0 * f) * ((nb + tNr[m]) - 2.0 * dot);
                if (m != t && D < bv) { bv = D; bi = m; }   // ascending m tie-break
            }
            tNNv[t] = bv; tNNi[t] = bi;
        }
        __syncthreads();
        if (t == 0) sNp = 0;
        __syncthreads();
        if (t < TAILSZ && tAct[t]) {
            int j = tNNi[t];
            if (j > t && j < TAILSZ && tNNi[j] == t) {      // mutual, t = keeper
                double sb = tSz[t], sj = tSz[j], s2 = sb + sj;
                double nr = 0.0;
                for (int d = 0; d < DIM; ++d) {
                    double v = (sb * tCent[d * TPAD + t] + sj * tCent[d * TPAD + j]) / s2;
                    tCent[d * TPAD + t] = v;
                    nr += v * v;
                }
                tSz[t] = s2; tNr[t] = nr;
                tAct[j] = 0;
                int r = atomicAdd(&g_mcount, 1);
                g_reci[r] = tCid[t]; g_recj[r] = tCid[j]; g_rech[r] = tNNv[t];
                atomicAdd(&sNp, 1);
            }
        }
        __syncthreads();
        a -= sNp;
        __syncthreads();
    }

    // ---- phase C: sort heights, apply n-k smallest, rank roots, scatter ----
    double* fD0 = tCent;                       // overlay: tail data dead now
    int* fI0 = (int*)(tCent + 2048);
    int* fI1 = (int*)(tCent + 3072);
    int* fI2 = (int*)(tCent + 4096);
    int* fI3 = (int*)(tCent + 5120);
    int* fI4 = (int*)(tCent + 6144);

    const int M = g_mcount;
    const int nsel = NPTS - k;
    __syncthreads();
    for (int e = t; e < NPTS; e += FNTHR) {
        fD0[e] = (e < M) ? g_rech[e] : (double)INFINITY;
        fI0[e] = e;
    }
    __syncthreads();
    for (int k2 = 2; k2 <= NPTS; k2 <<= 1) {
        for (int j2 = k2 >> 1; j2 > 0; j2 >>= 1) {
            for (int i = t; i < NPTS; i += FNTHR) {
                int ixj = i ^ j2;
                if (ixj > i) {
                    bool up = ((i & k2) == 0);
                    double a0_ = fD0[i], a1_ = fD0[ixj];
                    if (up ? (a0_ > a1_) : (a0_ < a1_)) {
                        fD0[i] = a1_; fD0[ixj] = a0_;
                        int ti_ = fI0[i]; fI0[i] = fI0[ixj]; fI0[ixj] = ti_;
                    }
                }
            }
            __syncthreads();
        }
    }
    for (int p = t; p < NPTS; p += FNTHR) fI1[p] = p;
    __syncthreads();
    for (int r = t; r < nsel; r += FNTHR) {
        int rec = fI0[r];
        fI1[g_recj[rec]] = g_reci[rec];   // each killed slot appears exactly once
    }
    __syncthreads();
    int* psrc = fI1; int* pdst = fI2;
    for (int it2 = 0; it2 < 11; ++it2) {          // 2^11 >= max chain depth
        for (int p = t; p < NPTS; p += FNTHR) pdst[p] = psrc[psrc[p]];
        __syncthreads();
        int* tp = psrc; psrc = pdst; pdst = tp;
    }
    for (int p = t; p < NPTS; p += FNTHR) fI3[p] = (psrc[p] == p) ? 1 : 0;
    __syncthreads();
    int* rsrc = fI3; int* rdst = fI4;
    for (int off = 1; off < NPTS; off <<= 1) {
        for (int p = t; p < NPTS; p += FNTHR)
            rdst[p] = rsrc[p] + ((p >= off) ? rsrc[p - off] : 0);
        __syncthreads();
        int* tp = rsrc; rsrc = rdst; rdst = tp;
    }
    for (int p = t; p < NPTS; p += FNTHR) {
        int lbl = rsrc[psrc[p]] - 1;              // rank of root, ascending
        out[(size_t)p * k + lbl] = 1.0f;
    }
}

// -------------------------------------------------------------- launch ----
extern "C" void kernel_launch(void* const* d_in, const int* in_sizes, int n_in,
                              void* d_out, int out_size, void* d_ws, size_t ws_size,
                              hipStream_t stream) {
    const float* x    = (const float*)d_in[0];
    const int*   kptr = (const int*)d_in[1];
    float*       out  = (float*)d_out;

    init_kernel<<<8, 256, 0, stream>>>(x);
    for (int r = 0; r < ROUNDS; ++r) {
        nn_pass<<<NPTS / TB, 512, 0, stream>>>();
        merge_pass<<<1, 1024, 0, stream>>>();
    }
    finisher<<<1, FNTHR, 0, stream>>>(kptr, out, out_size);
}

// Round 10
// 12729.623 us; speedup vs baseline: 8.2196x; 8.2196x over previous
//
#include <hip/hip_runtime.h>
#include <math.h>

#define NPTS   2048
#define DIM    96
#define PITCH  2048
#define TB     8
#define ROUNDS 16     // calibrated: a_r ~ 2048*0.85^r -> a_16 ~ 150 <= TAILSZ
#define TAILSZ 176
#define TPAD   178
#define FNTHR  512

// ---- fixed-slot state: slot index == cluster representative (min point) ----
__device__ double g_cent[DIM * PITCH];   // transposed centroids, in-place updates
__device__ double g_sz[NPTS];
__device__ double g_nrm[NPTS];           // ||mu||^2
__device__ int    g_act[NPTS];
__device__ int    g_cidx[NPTS];          // compacted active slot ids, ascending
__device__ double g_nnv[NPTS];
__device__ int    g_nni[NPTS];           // -1 for killed slots
__device__ int    g_reci[NPTS];          // merge records: keeper (smaller slot)
__device__ int    g_recj[NPTS];          //                killed (larger slot)
__device__ double g_rech[NPTS];          //                Ward height
__device__ int    g_a, g_done, g_mcount;

// ---------------------------------------------------------------- init ----
__global__ void init_kernel(const float* __restrict__ x,
                            float* __restrict__ out, int out_size) {
    int p = blockIdx.x * 256 + threadIdx.x;   // grid 8 x 256
    for (int i = p; i < out_size; i += 2048) out[i] = 0.0f;   // replaces memset
    if (p < NPTS) {
        double nr = 0.0;
        for (int d = 0; d < DIM; ++d) {
            double v = (double)x[p * DIM + d];
            g_cent[d * PITCH + p] = v;
            nr += v * v;
        }
        g_nrm[p] = nr; g_sz[p] = 1.0; g_act[p] = 1; g_cidx[p] = p;
        g_nni[p] = -1; g_nnv[p] = (double)INFINITY;
    }
    if (p == 0) { g_a = NPTS; g_done = 0; g_mcount = 0; }
}

// -------------------------------------------------------------- nn_pass ----
// (verbatim from the R6-passing kernel)
__global__ void __launch_bounds__(512) nn_pass() {
    if (g_done) return;
    const int a = g_a;
    const int tile0 = blockIdx.x * TB;
    if (tile0 >= a) return;
    const int t = threadIdx.x;

    __shared__ int    sIdx[TB];
    __shared__ double sMu[DIM * TB];
    __shared__ double sNb[TB], sSb[TB];
    __shared__ double sRedV[8 * TB];
    __shared__ int    sRedI[8 * TB];

    if (t < TB) {
        int cm   = tile0 + t;
        int orig = (cm < a) ? g_cidx[cm] : -1;
        sIdx[t] = orig;
        sNb[t]  = (orig >= 0) ? g_nrm[orig] : 0.0;
        sSb[t]  = (orig >= 0) ? g_sz[orig]  : 1.0;
    }
    __syncthreads();
    for (int e = t; e < DIM * TB; e += 512) {
        int col = sIdx[e & 7];
        sMu[e] = (col >= 0) ? g_cent[(e >> 3) * PITCH + col] : 0.0;
    }
    __syncthreads();

    int om[4]; bool vld[4];
#pragma unroll
    for (int q = 0; q < 4; ++q) {
        int m  = t + q * 512;
        vld[q] = (m < a);
        om[q]  = g_cidx[vld[q] ? m : (a - 1)];
    }
    double acc[4][TB];
#pragma unroll
    for (int q = 0; q < 4; ++q)
#pragma unroll
        for (int bi = 0; bi < TB; ++bi) acc[q][bi] = 0.0;

    for (int d = 0; d < DIM; ++d) {
        double mu[TB];
#pragma unroll
        for (int bi = 0; bi < TB; ++bi) mu[bi] = sMu[d * TB + bi];
        double x0 = g_cent[d * PITCH + om[0]];
        double x1 = g_cent[d * PITCH + om[1]];
        double x2 = g_cent[d * PITCH + om[2]];
        double x3 = g_cent[d * PITCH + om[3]];
#pragma unroll
        for (int bi = 0; bi < TB; ++bi) {
            acc[0][bi] += mu[bi] * x0;
            acc[1][bi] += mu[bi] * x1;
            acc[2][bi] += mu[bi] * x2;
            acc[3][bi] += mu[bi] * x3;
        }
    }

    double bv[TB]; int bidx[TB];
#pragma unroll
    for (int bi = 0; bi < TB; ++bi) { bv[bi] = (double)INFINITY; bidx[bi] = 0x7FFFFFFF; }
#pragma unroll
    for (int q = 0; q < 4; ++q) {
        if (!vld[q]) continue;
        int    cm = t + q * 512;
        double sm = g_sz[om[q]], nm = g_nrm[om[q]];
#pragma unroll
        for (int bi = 0; bi < TB; ++bi) {
            double f = (sSb[bi] * sm) / (sSb[bi] + sm);
            double D = (2.0 * f) * ((sNb[bi] + nm) - 2.0 * acc[q][bi]);
            if (cm != tile0 + bi && D < bv[bi]) { bv[bi] = D; bidx[bi] = om[q]; }
        }
    }

    const int lane = t & 63, w = t >> 6;
#pragma unroll
    for (int bi = 0; bi < TB; ++bi) {
        double v = bv[bi]; int ix = bidx[bi];
        for (int off = 1; off < 64; off <<= 1) {
            double ov = __shfl_xor(v, off);
            int    oi = __shfl_xor(ix, off);
            if (ov < v || (ov == v && oi < ix)) { v = ov; ix = oi; }
        }
        if (lane == 0) { sRedV[w * TB + bi] = v; sRedI[w * TB + bi] = ix; }
    }
    __syncthreads();
    if (t < TB && tile0 + t < a) {
        double v = sRedV[t]; int ix = sRedI[t];
        for (int w2 = 1; w2 < 8; ++w2) {
            double ov = sRedV[w2 * TB + t]; int oi = sRedI[w2 * TB + t];
            if (ov < v || (ov == v && oi < ix)) { v = ov; ix = oi; }
        }
        g_nnv[sIdx[t]] = v;
        g_nni[sIdx[t]] = ix;
    }
}

// ----------------------------------------------------------- merge_pass ----
// (verbatim R6 logic; stop condition a2 <= TAILSZ)
__global__ void __launch_bounds__(1024) merge_pass() {
    if (g_done) return;
    __shared__ int sWave[16];
    const int t = threadIdx.x, lane = t & 63, w = t >> 6;

    for (int b = t; b < NPTS; b += 1024) {
        int j = g_nni[b];
        if (j > b && j < NPTS && g_nni[j] == b) {   // mutual pair, b = keeper
            int r = atomicAdd(&g_mcount, 1);
            g_reci[r] = b; g_recj[r] = j; g_rech[r] = g_nnv[b];
            double sb = g_sz[b], sj = g_sz[j], s2 = sb + sj;
            double nr = 0.0;
            for (int d = 0; d < DIM; ++d) {
                double v = (sb * g_cent[d * PITCH + b] + sj * g_cent[d * PITCH + j]) / s2;
                g_cent[d * PITCH + b] = v;
                nr += v * v;
            }
            g_sz[b] = s2; g_nrm[b] = nr;
            g_act[j] = 0; g_nni[j] = -1; g_nnv[j] = (double)INFINITY;
        }
    }
    __syncthreads();

    int e0 = 2 * t, e1 = 2 * t + 1;
    int c0 = g_act[e0], c1 = g_act[e1];
    int sum = c0 + c1;
    int v = sum;
    for (int off = 1; off < 64; off <<= 1) {
        int o = __shfl_up(v, off);
        if (lane >= off) v += o;
    }
    if (lane == 63) sWave[w] = v;
    __syncthreads();
    if (t == 0) {
        int run = 0;
        for (int i = 0; i < 16; ++i) { int x = sWave[i]; sWave[i] = run; run += x; }
    }
    __syncthreads();
    int base = sWave[w] + (v - sum);
    if (c0) g_cidx[base]      = e0;
    if (c1) g_cidx[base + c0] = e1;
    if (t == 1023) {
        int a2 = base + sum;
        g_a = a2;
        g_done = (a2 <= TAILSZ) ? 1 : 0;
    }
}

// Per-block order-preserving compaction of g_act -> sCidx (512 threads).
__device__ __forceinline__ int block_compact(unsigned short* sCidx, int* sWS) {
    const int t = threadIdx.x, lane = t & 63, w = t >> 6;
    int base = t * 4;
    int c0 = g_act[base], c1 = g_act[base + 1], c2 = g_act[base + 2], c3 = g_act[base + 3];
    int sum = c0 + c1 + c2 + c3;
    int v = sum;
#pragma unroll
    for (int off = 1; off < 64; off <<= 1) {
        int o = __shfl_up(v, off);
        if (lane >= off) v += o;
    }
    if (lane == 63) sWS[w] = v;
    __syncthreads();
    if (t == 0) {
        int run = 0;
#pragma unroll
        for (int i = 0; i < 8; ++i) { int x = sWS[i]; sWS[i] = run; run += x; }
        sWS[8] = run;
    }
    __syncthreads();
    int ex = sWS[w] + (v - sum);
    if (c0) sCidx[ex] = (unsigned short)base;       ex += c0;
    if (c1) sCidx[ex] = (unsigned short)(base + 1); ex += c1;
    if (c2) sCidx[ex] = (unsigned short)(base + 2); ex += c2;
    if (c3) sCidx[ex] = (unsigned short)(base + 3); ex += c3;
    int a = sWS[8];
    __syncthreads();
    return a;
}

// ------------------------------------------------------------- finisher ----
// A: tiled nn_pass-style MNN rounds (one block, LDS row tiles) while a>TAILSZ.
// B: LDS-resident tail, 2 candidate-groups per row, down to a == 1.
// C: sort heights, cut n-k smallest, union-find, rank roots, scatter.
__global__ void __launch_bounds__(FNTHR) finisher(const int* __restrict__ kptr,
                                                  float* __restrict__ out) {
    __shared__ unsigned short sCidx[NPTS];     //   4 KB
    __shared__ int    sWS[16];
    __shared__ int    sNp;
    __shared__ double tCent[DIM * TPAD];       // 133.5 KB arena (A/B/C overlays)
    __shared__ double tSz[TAILSZ], tNr[TAILSZ], tNNv[TAILSZ];
    __shared__ int    tNNi[TAILSZ], tCid[TAILSZ];
    __shared__ unsigned char tAct[TAILSZ];
    __shared__ double pV[2 * TAILSZ];          // phase-B group partials
    __shared__ int    pI[2 * TAILSZ];

    const int t = threadIdx.x, lane = t & 63, w = t >> 6;
    const int k = *kptr;

    int a = block_compact(sCidx, sWS);

    // ---- phase A: tiled MNN rounds in-block (insurance; usually 0-1 rounds) ----
    {
        double* aD0   = tCent;                       // [2048] nn val by position
        int*    aI0   = (int*)(tCent + 2048);        // [2048] nn pos by position
        double* aMu   = tCent + 3072;                // [8*96] row tile
        double* aNb   = tCent + 3840;                // [8]
        double* aSb   = tCent + 3848;                // [8]
        double* aRedV = tCent + 3856;                // [64]
        int*    aRedI = (int*)(tCent + 3920);        // [64]
        int*    aId   = (int*)(tCent + 3952);        // [8]

        while (a > TAILSZ) {
            for (int tile0 = 0; tile0 < a; tile0 += TB) {
                __syncthreads();
                if (t < TB) {
                    int cm   = tile0 + t;
                    int orig = (cm < a) ? (int)sCidx[cm] : -1;
                    aId[t] = orig;
                    aNb[t] = (orig >= 0) ? g_nrm[orig] : 0.0;
                    aSb[t] = (orig >= 0) ? g_sz[orig]  : 1.0;
                }
                __syncthreads();
                for (int e = t; e < DIM * TB; e += FNTHR) {
                    int col = aId[e & 7];
                    aMu[e] = (col >= 0) ? g_cent[(e >> 3) * PITCH + col] : 0.0;
                }
                __syncthreads();

                int om[4]; bool vld[4];
#pragma unroll
                for (int q = 0; q < 4; ++q) {
                    int m  = t + q * FNTHR;
                    vld[q] = (m < a);
                    om[q]  = (int)sCidx[vld[q] ? m : (a - 1)];
                }
                double acc[4][TB];
#pragma unroll
                for (int q = 0; q < 4; ++q)
#pragma unroll
                    for (int bi = 0; bi < TB; ++bi) acc[q][bi] = 0.0;

                for (int d = 0; d < DIM; ++d) {
                    double mu[TB];
#pragma unroll
                    for (int bi = 0; bi < TB; ++bi) mu[bi] = aMu[d * TB + bi];
                    double x0 = g_cent[d * PITCH + om[0]];
                    double x1 = g_cent[d * PITCH + om[1]];
                    double x2 = g_cent[d * PITCH + om[2]];
                    double x3 = g_cent[d * PITCH + om[3]];
#pragma unroll
                    for (int bi = 0; bi < TB; ++bi) {
                        acc[0][bi] += mu[bi] * x0;
                        acc[1][bi] += mu[bi] * x1;
                        acc[2][bi] += mu[bi] * x2;
                        acc[3][bi] += mu[bi] * x3;
                    }
                }

                double bv[TB]; int bidx[TB];
#pragma unroll
                for (int bi = 0; bi < TB; ++bi) { bv[bi] = (double)INFINITY; bidx[bi] = 0x7FFFFFFF; }
#pragma unroll
                for (int q = 0; q < 4; ++q) {
                    if (!vld[q]) continue;
                    int    cm = t + q * FNTHR;
                    double sm = g_sz[om[q]], nm = g_nrm[om[q]];
#pragma unroll
                    for (int bi = 0; bi < TB; ++bi) {
                        double f = (aSb[bi] * sm) / (aSb[bi] + sm);
                        double D = (2.0 * f) * ((aNb[bi] + nm) - 2.0 * acc[q][bi]);
                        if (cm != tile0 + bi && D < bv[bi]) { bv[bi] = D; bidx[bi] = cm; }
                    }
                }
#pragma unroll
                for (int bi = 0; bi < TB; ++bi) {
                    double v = bv[bi]; int ix = bidx[bi];
                    for (int off = 1; off < 64; off <<= 1) {
                        double ov = __shfl_xor(v, off);
                        int    oi = __shfl_xor(ix, off);
                        if (ov < v || (ov == v && oi < ix)) { v = ov; ix = oi; }
                    }
                    if (lane == 0) { aRedV[w * TB + bi] = v; aRedI[w * TB + bi] = ix; }
                }
                __syncthreads();
                if (t < TB && tile0 + t < a) {
                    double v = aRedV[t]; int ix = aRedI[t];
                    for (int w2 = 1; w2 < 8; ++w2) {
                        double ov = aRedV[w2 * TB + t]; int oi = aRedI[w2 * TB + t];
                        if (ov < v || (ov == v && oi < ix)) { v = ov; ix = oi; }
                    }
                    aD0[tile0 + t] = v;
                    aI0[tile0 + t] = ix;
                }
            }
            __syncthreads();
            if (t == 0) sNp = 0;
            __syncthreads();
            for (int c = t; c < a; c += FNTHR) {
                int jc = aI0[c];
                if (jc > c && jc < a && aI0[jc] == c) {   // mutual by position
                    int b = (int)sCidx[c], j = (int)sCidx[jc];
                    double sb = g_sz[b], sj = g_sz[j], s2 = sb + sj;
                    double nr = 0.0;
                    for (int d = 0; d < DIM; ++d) {
                        double v = (sb * g_cent[d * PITCH + b] + sj * g_cent[d * PITCH + j]) / s2;
                        g_cent[d * PITCH + b] = v; nr += v * v;
                    }
                    g_sz[b] = s2; g_nrm[b] = nr; g_act[j] = 0;
                    int r = atomicAdd(&g_mcount, 1);
                    g_reci[r] = b; g_recj[r] = j; g_rech[r] = aD0[c];
                    atomicAdd(&sNp, 1);
                }
            }
            __syncthreads();
            a = block_compact(sCidx, sWS);
        }
    }

    // ---- phase B: LDS-resident tail, 2 candidate-groups per row ----
    const int a0 = a;
    for (int p = t; p < TAILSZ; p += FNTHR) {
        bool vv = (p < a0);
        int orig = vv ? (int)sCidx[p] : 0;
        for (int d = 0; d < DIM; ++d)
            tCent[d * TPAD + p] = vv ? g_cent[d * PITCH + orig] : 0.0;
        tSz[p]  = vv ? g_sz[orig]  : 1.0;
        tNr[p]  = vv ? g_nrm[orig] : 0.0;
        tCid[p] = orig;
        tAct[p] = vv ? 1 : 0;
    }
    __syncthreads();

    int guard = 0;
    while (a > 1 && guard < NPTS) {
        ++guard;
        if (t < 2 * TAILSZ) {
            int r = t % TAILSZ, g = t / TAILSZ;
            if (tAct[r]) {
                double sb = tSz[r], nb = tNr[r];
                double bv = (double)INFINITY; int bi = 0x7FFFFFFF;
                int m0 = g * (TAILSZ / 2), m1 = m0 + (TAILSZ / 2);
                for (int m = m0; m < m1; ++m) {
                    if (!tAct[m]) continue;
                    double d0 = 0.0, d1 = 0.0, d2 = 0.0, d3 = 0.0;
#pragma unroll
                    for (int d = 0; d < DIM; d += 4) {     // 4-way split, bit-symmetric
                        d0 += tCent[(d    ) * TPAD + r] * tCent[(d    ) * TPAD + m];
                        d1 += tCent[(d + 1) * TPAD + r] * tCent[(d + 1) * TPAD + m];
                        d2 += tCent[(d + 2) * TPAD + r] * tCent[(d + 2) * TPAD + m];
                        d3 += tCent[(d + 3) * TPAD + r] * tCent[(d + 3) * TPAD + m];
                    }
                    double dot = (d0 + d1) + (d2 + d3);
                    double sm = tSz[m];
                    double f = (sb * sm) / (sb + sm);
                    double D = (2.0 * f) * ((nb + tNr[m]) - 2.0 * dot);
                    if (m != r && D < bv) { bv = D; bi = m; }   // ascending m tie-break
                }
                pV[g * TAILSZ + r] = bv;
                pI[g * TAILSZ + r] = bi;
            }
        }
        __syncthreads();
        if (t == 0) sNp = 0;
        __syncthreads();
        if (t < TAILSZ && tAct[t]) {
            double bv = pV[t]; int bi = pI[t];              // group 0 = smaller m
            if (pV[TAILSZ + t] < bv) { bv = pV[TAILSZ + t]; bi = pI[TAILSZ + t]; }
            tNNv[t] = bv; tNNi[t] = bi;
        }
        __syncthreads();
        if (t < TAILSZ && tAct[t]) {
            int j = tNNi[t];
            if (j > t && j < TAILSZ && tNNi[j] == t) {      // mutual, t = keeper
                double sb = tSz[t], sj = tSz[j], s2 = sb + sj;
                double nr = 0.0;
                for (int d = 0; d < DIM; ++d) {
                    double v = (sb * tCent[d * TPAD + t] + sj * tCent[d * TPAD + j]) / s2;
                    tCent[d * TPAD + t] = v;
                    nr += v * v;
                }
                tSz[t] = s2; tNr[t] = nr;
                tAct[j] = 0;
                int r = atomicAdd(&g_mcount, 1);
                g_reci[r] = tCid[t]; g_recj[r] = tCid[j]; g_rech[r] = tNNv[t];
                atomicAdd(&sNp, 1);
            }
        }
        __syncthreads();
        a -= sNp;
        __syncthreads();
    }

    // ---- phase C: sort heights, apply n-k smallest, rank roots, scatter ----
    double* fD0 = tCent;                       // overlay: tail data dead now
    int* fI0 = (int*)(tCent + 2048);
    int* fI1 = (int*)(tCent + 3072);
    int* fI2 = (int*)(tCent + 4096);
    int* fI3 = (int*)(tCent + 5120);
    int* fI4 = (int*)(tCent + 6144);

    const int M = g_mcount;
    const int nsel = NPTS - k;
    __syncthreads();
    for (int e = t; e < NPTS; e += FNTHR) {
        fD0[e] = (e < M) ? g_rech[e] : (double)INFINITY;
        fI0[e] = e;
    }
    __syncthreads();
    for (int k2 = 2; k2 <= NPTS; k2 <<= 1) {
        for (int j2 = k2 >> 1; j2 > 0; j2 >>= 1) {
            for (int i = t; i < NPTS; i += FNTHR) {
                int ixj = i ^ j2;
                if (ixj > i) {
                    bool up = ((i & k2) == 0);
                    double a0_ = fD0[i], a1_ = fD0[ixj];
                    if (up ? (a0_ > a1_) : (a0_ < a1_)) {
                        fD0[i] = a1_; fD0[ixj] = a0_;
                        int ti_ = fI0[i]; fI0[i] = fI0[ixj]; fI0[ixj] = ti_;
                    }
                }
            }
            __syncthreads();
        }
    }
    for (int p = t; p < NPTS; p += FNTHR) fI1[p] = p;
    __syncthreads();
    for (int r = t; r < nsel; r += FNTHR) {
        int rec = fI0[r];
        fI1[g_recj[rec]] = g_reci[rec];   // each killed slot appears exactly once
    }
    __syncthreads();
    int* psrc = fI1; int* pdst = fI2;
    for (int it2 = 0; it2 < 11; ++it2) {          // 2^11 >= max chain depth
        for (int p = t; p < NPTS; p += FNTHR) pdst[p] = psrc[psrc[p]];
        __syncthreads();
        int* tp = psrc; psrc = pdst; pdst = tp;
    }
    for (int p = t; p < NPTS; p += FNTHR) fI3[p] = (psrc[p] == p) ? 1 : 0;
    __syncthreads();
    int* rsrc = fI3; int* rdst = fI4;
    for (int off = 1; off < NPTS; off <<= 1) {
        for (int p = t; p < NPTS; p += FNTHR)
            rdst[p] = rsrc[p] + ((p >= off) ? rsrc[p - off] : 0);
        __syncthreads();
        int* tp = rsrc; rsrc = rdst; rdst = tp;
    }
    for (int p = t; p < NPTS; p += FNTHR) {
        int lbl = rsrc[psrc[p]] - 1;              // rank of root, ascending
        out[(size_t)p * k + lbl] = 1.0f;
    }
}

// -------------------------------------------------------------- launch ----
extern "C" void kernel_launch(void* const* d_in, const int* in_sizes, int n_in,
                              void* d_out, int out_size, void* d_ws, size_t ws_size,
                              hipStream_t stream) {
    const float* x    = (const float*)d_in[0];
    const int*   kptr = (const int*)d_in[1];
    float*       out  = (float*)d_out;

    init_kernel<<<8, 256, 0, stream>>>(x, out, out_size);
    for (int r = 0; r < ROUNDS; ++r) {
        nn_pass<<<NPTS / TB, 512, 0, stream>>>();
        merge_pass<<<1, 1024, 0, stream>>>();
    }
    finisher<<<1, FNTHR, 0, stream>>>(kptr, out);
}

// Round 11
// 12486.771 us; speedup vs baseline: 8.3795x; 1.0194x over previous
//
#include <hip/hip_runtime.h>
#include <math.h>

#define NPTS   2048
#define DIM    96
#define PITCH  2048
#define TB     8
#define ROUNDS 16     // calibrated: a_r ~ 2048*0.85^r -> a_16 ~ 150 <= TAILSZ
#define TAILSZ 176
#define TPAD   178
#define FNTHR  512

// ---- fixed-slot state: slot index == cluster representative (min point) ----
__device__ double g_cent[DIM * PITCH];   // transposed centroids, in-place updates
__device__ double g_sz[NPTS];
__device__ double g_nrm[NPTS];           // ||mu||^2
__device__ int    g_act[NPTS];
__device__ int    g_cidx[NPTS];          // compacted active slot ids, ascending
__device__ double g_nnv[NPTS];
__device__ int    g_nni[NPTS];           // -1 for killed slots
__device__ int    g_reci[NPTS];          // merge records: keeper (smaller slot)
__device__ int    g_recj[NPTS];          //                killed (larger slot)
__device__ double g_rech[NPTS];          //                Ward height
__device__ int    g_a, g_done, g_mcount;

// ---------------------------------------------------------------- init ----
__global__ void init_kernel(const float* __restrict__ x,
                            float* __restrict__ out, int out_size) {
    int p = blockIdx.x * 256 + threadIdx.x;   // grid 8 x 256
    for (int i = p; i < out_size; i += 2048) out[i] = 0.0f;   // replaces memset
    if (p < NPTS) {
        double nr = 0.0;
        for (int d = 0; d < DIM; ++d) {
            double v = (double)x[p * DIM + d];
            g_cent[d * PITCH + p] = v;
            nr += v * v;
        }
        g_nrm[p] = nr; g_sz[p] = 1.0; g_act[p] = 1; g_cidx[p] = p;
        g_nni[p] = -1; g_nnv[p] = (double)INFINITY;
    }
    if (p == 0) { g_a = NPTS; g_done = 0; g_mcount = 0; }
}

// -------------------------------------------------------------- nn_pass ----
// (verbatim from the R6-passing kernel)
__global__ void __launch_bounds__(512) nn_pass() {
    if (g_done) return;
    const int a = g_a;
    const int tile0 = blockIdx.x * TB;
    if (tile0 >= a) return;
    const int t = threadIdx.x;

    __shared__ int    sIdx[TB];
    __shared__ double sMu[DIM * TB];
    __shared__ double sNb[TB], sSb[TB];
    __shared__ double sRedV[8 * TB];
    __shared__ int    sRedI[8 * TB];

    if (t < TB) {
        int cm   = tile0 + t;
        int orig = (cm < a) ? g_cidx[cm] : -1;
        sIdx[t] = orig;
        sNb[t]  = (orig >= 0) ? g_nrm[orig] : 0.0;
        sSb[t]  = (orig >= 0) ? g_sz[orig]  : 1.0;
    }
    __syncthreads();
    for (int e = t; e < DIM * TB; e += 512) {
        int col = sIdx[e & 7];
        sMu[e] = (col >= 0) ? g_cent[(e >> 3) * PITCH + col] : 0.0;
    }
    __syncthreads();

    int om[4]; bool vld[4];
#pragma unroll
    for (int q = 0; q < 4; ++q) {
        int m  = t + q * 512;
        vld[q] = (m < a);
        om[q]  = g_cidx[vld[q] ? m : (a - 1)];
    }
    double acc[4][TB];
#pragma unroll
    for (int q = 0; q < 4; ++q)
#pragma unroll
        for (int bi = 0; bi < TB; ++bi) acc[q][bi] = 0.0;

    for (int d = 0; d < DIM; ++d) {
        double mu[TB];
#pragma unroll
        for (int bi = 0; bi < TB; ++bi) mu[bi] = sMu[d * TB + bi];
        double x0 = g_cent[d * PITCH + om[0]];
        double x1 = g_cent[d * PITCH + om[1]];
        double x2 = g_cent[d * PITCH + om[2]];
        double x3 = g_cent[d * PITCH + om[3]];
#pragma unroll
        for (int bi = 0; bi < TB; ++bi) {
            acc[0][bi] += mu[bi] * x0;
            acc[1][bi] += mu[bi] * x1;
            acc[2][bi] += mu[bi] * x2;
            acc[3][bi] += mu[bi] * x3;
        }
    }

    double bv[TB]; int bidx[TB];
#pragma unroll
    for (int bi = 0; bi < TB; ++bi) { bv[bi] = (double)INFINITY; bidx[bi] = 0x7FFFFFFF; }
#pragma unroll
    for (int q = 0; q < 4; ++q) {
        if (!vld[q]) continue;
        int    cm = t + q * 512;
        double sm = g_sz[om[q]], nm = g_nrm[om[q]];
#pragma unroll
        for (int bi = 0; bi < TB; ++bi) {
            double f = (sSb[bi] * sm) / (sSb[bi] + sm);
            double D = (2.0 * f) * ((sNb[bi] + nm) - 2.0 * acc[q][bi]);
            if (cm != tile0 + bi && D < bv[bi]) { bv[bi] = D; bidx[bi] = om[q]; }
        }
    }

    const int lane = t & 63, w = t >> 6;
#pragma unroll
    for (int bi = 0; bi < TB; ++bi) {
        double v = bv[bi]; int ix = bidx[bi];
        for (int off = 1; off < 64; off <<= 1) {
            double ov = __shfl_xor(v, off);
            int    oi = __shfl_xor(ix, off);
            if (ov < v || (ov == v && oi < ix)) { v = ov; ix = oi; }
        }
        if (lane == 0) { sRedV[w * TB + bi] = v; sRedI[w * TB + bi] = ix; }
    }
    __syncthreads();
    if (t < TB && tile0 + t < a) {
        double v = sRedV[t]; int ix = sRedI[t];
        for (int w2 = 1; w2 < 8; ++w2) {
            double ov = sRedV[w2 * TB + t]; int oi = sRedI[w2 * TB + t];
            if (ov < v || (ov == v && oi < ix)) { v = ov; ix = oi; }
        }
        g_nnv[sIdx[t]] = v;
        g_nni[sIdx[t]] = ix;
    }
}

// ----------------------------------------------------------- merge_pass ----
// (verbatim R6 logic; stop condition a2 <= TAILSZ)
__global__ void __launch_bounds__(1024) merge_pass() {
    if (g_done) return;
    __shared__ int sWave[16];
    const int t = threadIdx.x, lane = t & 63, w = t >> 6;

    for (int b = t; b < NPTS; b += 1024) {
        int j = g_nni[b];
        if (j > b && j < NPTS && g_nni[j] == b) {   // mutual pair, b = keeper
            int r = atomicAdd(&g_mcount, 1);
            g_reci[r] = b; g_recj[r] = j; g_rech[r] = g_nnv[b];
            double sb = g_sz[b], sj = g_sz[j], s2 = sb + sj;
            double nr = 0.0;
            for (int d = 0; d < DIM; ++d) {
                double v = (sb * g_cent[d * PITCH + b] + sj * g_cent[d * PITCH + j]) / s2;
                g_cent[d * PITCH + b] = v;
                nr += v * v;
            }
            g_sz[b] = s2; g_nrm[b] = nr;
            g_act[j] = 0; g_nni[j] = -1; g_nnv[j] = (double)INFINITY;
        }
    }
    __syncthreads();

    int e0 = 2 * t, e1 = 2 * t + 1;
    int c0 = g_act[e0], c1 = g_act[e1];
    int sum = c0 + c1;
    int v = sum;
    for (int off = 1; off < 64; off <<= 1) {
        int o = __shfl_up(v, off);
        if (lane >= off) v += o;
    }
    if (lane == 63) sWave[w] = v;
    __syncthreads();
    if (t == 0) {
        int run = 0;
        for (int i = 0; i < 16; ++i) { int x = sWave[i]; sWave[i] = run; run += x; }
    }
    __syncthreads();
    int base = sWave[w] + (v - sum);
    if (c0) g_cidx[base]      = e0;
    if (c1) g_cidx[base + c0] = e1;
    if (t == 1023) {
        int a2 = base + sum;
        g_a = a2;
        g_done = (a2 <= TAILSZ) ? 1 : 0;
    }
}

// Per-block order-preserving compaction of g_act -> sCidx (512 threads).
__device__ __forceinline__ int block_compact(unsigned short* sCidx, int* sWS) {
    const int t = threadIdx.x, lane = t & 63, w = t >> 6;
    int base = t * 4;
    int c0 = g_act[base], c1 = g_act[base + 1], c2 = g_act[base + 2], c3 = g_act[base + 3];
    int sum = c0 + c1 + c2 + c3;
    int v = sum;
#pragma unroll
    for (int off = 1; off < 64; off <<= 1) {
        int o = __shfl_up(v, off);
        if (lane >= off) v += o;
    }
    if (lane == 63) sWS[w] = v;
    __syncthreads();
    if (t == 0) {
        int run = 0;
#pragma unroll
        for (int i = 0; i < 8; ++i) { int x = sWS[i]; sWS[i] = run; run += x; }
        sWS[8] = run;
    }
    __syncthreads();
    int ex = sWS[w] + (v - sum);
    if (c0) sCidx[ex] = (unsigned short)base;       ex += c0;
    if (c1) sCidx[ex] = (unsigned short)(base + 1); ex += c1;
    if (c2) sCidx[ex] = (unsigned short)(base + 2); ex += c2;
    if (c3) sCidx[ex] = (unsigned short)(base + 3); ex += c3;
    int a = sWS[8];
    __syncthreads();
    return a;
}

// ------------------------------------------------------------- finisher ----
// A: tiled MNN rounds (insurance) while a > TAILSZ.
// B: NN-CHAIN in LDS from a <= 176 to the full dendrogram (a == 1).
// C: sort heights, cut n-k smallest, union-find, rank roots, scatter.
__global__ void __launch_bounds__(FNTHR) finisher(const int* __restrict__ kptr,
                                                  float* __restrict__ out) {
    __shared__ unsigned short sCidx[NPTS];     //   4 KB
    __shared__ int    sWS[16];
    __shared__ int    sNp;
    __shared__ double tCent[DIM * TPAD];       // 133.5 KB arena (A/B/C overlays)
    __shared__ double tSz[TAILSZ], tNr[TAILSZ];
    __shared__ double chainD[TAILSZ + 2];
    __shared__ int    chainP[TAILSZ + 2];
    __shared__ int    tCid[TAILSZ];
    __shared__ unsigned char tAct[TAILSZ];
    __shared__ double wRedV[8];
    __shared__ int    wRedI[8];
    __shared__ double sNNv;
    __shared__ int    sNNi;
    __shared__ double pSq[128];
    __shared__ int    sLen, sA;

    const int t = threadIdx.x, lane = t & 63, w = t >> 6;
    const int k = *kptr;

    int a = block_compact(sCidx, sWS);

    // ---- phase A: tiled MNN rounds in-block (insurance; usually 0 rounds) ----
    {
        double* aD0   = tCent;                       // [2048] nn val by position
        int*    aI0   = (int*)(tCent + 2048);        // [2048] nn pos by position
        double* aMu   = tCent + 3072;                // [8*96] row tile
        double* aNb   = tCent + 3840;                // [8]
        double* aSb   = tCent + 3848;                // [8]
        double* aRedV = tCent + 3856;                // [64]
        int*    aRedI = (int*)(tCent + 3920);        // [64]
        int*    aId   = (int*)(tCent + 3952);        // [8]

        while (a > TAILSZ) {
            for (int tile0 = 0; tile0 < a; tile0 += TB) {
                __syncthreads();
                if (t < TB) {
                    int cm   = tile0 + t;
                    int orig = (cm < a) ? (int)sCidx[cm] : -1;
                    aId[t] = orig;
                    aNb[t] = (orig >= 0) ? g_nrm[orig] : 0.0;
                    aSb[t] = (orig >= 0) ? g_sz[orig]  : 1.0;
                }
                __syncthreads();
                for (int e = t; e < DIM * TB; e += FNTHR) {
                    int col = aId[e & 7];
                    aMu[e] = (col >= 0) ? g_cent[(e >> 3) * PITCH + col] : 0.0;
                }
                __syncthreads();

                int om[4]; bool vld[4];
#pragma unroll
                for (int q = 0; q < 4; ++q) {
                    int m  = t + q * FNTHR;
                    vld[q] = (m < a);
                    om[q]  = (int)sCidx[vld[q] ? m : (a - 1)];
                }
                double acc[4][TB];
#pragma unroll
                for (int q = 0; q < 4; ++q)
#pragma unroll
                    for (int bi = 0; bi < TB; ++bi) acc[q][bi] = 0.0;

                for (int d = 0; d < DIM; ++d) {
                    double mu[TB];
#pragma unroll
                    for (int bi = 0; bi < TB; ++bi) mu[bi] = aMu[d * TB + bi];
                    double x0 = g_cent[d * PITCH + om[0]];
                    double x1 = g_cent[d * PITCH + om[1]];
                    double x2 = g_cent[d * PITCH + om[2]];
                    double x3 = g_cent[d * PITCH + om[3]];
#pragma unroll
                    for (int bi = 0; bi < TB; ++bi) {
                        acc[0][bi] += mu[bi] * x0;
                        acc[1][bi] += mu[bi] * x1;
                        acc[2][bi] += mu[bi] * x2;
                        acc[3][bi] += mu[bi] * x3;
                    }
                }

                double bv[TB]; int bidx[TB];
#pragma unroll
                for (int bi = 0; bi < TB; ++bi) { bv[bi] = (double)INFINITY; bidx[bi] = 0x7FFFFFFF; }
#pragma unroll
                for (int q = 0; q < 4; ++q) {
                    if (!vld[q]) continue;
                    int    cm = t + q * FNTHR;
                    double sm = g_sz[om[q]], nm = g_nrm[om[q]];
#pragma unroll
                    for (int bi = 0; bi < TB; ++bi) {
                        double f = (aSb[bi] * sm) / (aSb[bi] + sm);
                        double D = (2.0 * f) * ((aNb[bi] + nm) - 2.0 * acc[q][bi]);
                        if (cm != tile0 + bi && D < bv[bi]) { bv[bi] = D; bidx[bi] = cm; }
                    }
                }
#pragma unroll
                for (int bi = 0; bi < TB; ++bi) {
                    double v = bv[bi]; int ix = bidx[bi];
                    for (int off = 1; off < 64; off <<= 1) {
                        double ov = __shfl_xor(v, off);
                        int    oi = __shfl_xor(ix, off);
                        if (ov < v || (ov == v && oi < ix)) { v = ov; ix = oi; }
                    }
                    if (lane == 0) { aRedV[w * TB + bi] = v; aRedI[w * TB + bi] = ix; }
                }
                __syncthreads();
                if (t < TB && tile0 + t < a) {
                    double v = aRedV[t]; int ix = aRedI[t];
                    for (int w2 = 1; w2 < 8; ++w2) {
                        double ov = aRedV[w2 * TB + t]; int oi = aRedI[w2 * TB + t];
                        if (ov < v || (ov == v && oi < ix)) { v = ov; ix = oi; }
                    }
                    aD0[tile0 + t] = v;
                    aI0[tile0 + t] = ix;
                }
            }
            __syncthreads();
            if (t == 0) sNp = 0;
            __syncthreads();
            for (int c = t; c < a; c += FNTHR) {
                int jc = aI0[c];
                if (jc > c && jc < a && aI0[jc] == c) {   // mutual by position
                    int b = (int)sCidx[c], j = (int)sCidx[jc];
                    double sb = g_sz[b], sj = g_sz[j], s2 = sb + sj;
                    double nr = 0.0;
                    for (int d = 0; d < DIM; ++d) {
                        double v = (sb * g_cent[d * PITCH + b] + sj * g_cent[d * PITCH + j]) / s2;
                        g_cent[d * PITCH + b] = v; nr += v * v;
                    }
                    g_sz[b] = s2; g_nrm[b] = nr; g_act[j] = 0;
                    int r = atomicAdd(&g_mcount, 1);
                    g_reci[r] = b; g_recj[r] = j; g_rech[r] = aD0[c];
                    atomicAdd(&sNp, 1);
                }
            }
            __syncthreads();
            a = block_compact(sCidx, sWS);
        }
    }

    // ---- phase B: NN-CHAIN over the LDS-resident tail ----
    const int a0 = a;
    for (int p = t; p < TAILSZ; p += FNTHR) {
        bool vv = (p < a0);
        int orig = vv ? (int)sCidx[p] : 0;
        for (int d = 0; d < DIM; ++d)
            tCent[d * TPAD + p] = vv ? g_cent[d * PITCH + orig] : 0.0;
        tSz[p]  = vv ? g_sz[orig]  : 1.0;
        tNr[p]  = vv ? g_nrm[orig] : 0.0;
        tCid[p] = orig;
        tAct[p] = vv ? 1 : 0;
    }
    if (t == 0) { sLen = 0; sA = a0; }
    __syncthreads();

    for (int guard = 0; guard < 8 * NPTS; ++guard) {
        int aa  = sA;                 // post-barrier reads: uniform
        int len = sLen;
        if (aa <= 1) break;

        if (len == 0) {
            // restart: pick smallest active position (parallel lexmin on idx)
            double v0 = (t < TAILSZ && tAct[t]) ? 0.0 : (double)INFINITY;
            int    i0 = (t < TAILSZ && tAct[t]) ? t : 0x7FFFFFFF;
            {   // block lexmin -> (sNNv, sNNi)
                double v = v0; int ix = i0;
                for (int off = 1; off < 64; off <<= 1) {
                    double ov = __shfl_xor(v, off);
                    int    oi = __shfl_xor(ix, off);
                    if (ov < v || (ov == v && oi < ix)) { v = ov; ix = oi; }
                }
                if (lane == 0) { wRedV[w] = v; wRedI[w] = ix; }
                __syncthreads();
                if (t == 0) {
                    double bv = wRedV[0]; int bi = wRedI[0];
                    for (int i = 1; i < 8; ++i)
                        if (wRedV[i] < bv || (wRedV[i] == bv && wRedI[i] < bi)) { bv = wRedV[i]; bi = wRedI[i]; }
                    chainP[0] = bi; chainD[0] = (double)INFINITY; sLen = 1;
                }
                __syncthreads();
            }
            len = 1;
        }
        const int top = chainP[len - 1];

        // NN search: thread t = candidate position t
        double Dv = (double)INFINITY; int Pi = 0x7FFFFFFF;
        if (t < TAILSZ && tAct[t] && t != top) {
            double d0 = 0.0, d1 = 0.0, d2 = 0.0, d3 = 0.0;
#pragma unroll
            for (int d = 0; d < DIM; d += 4) {        // 4-way split, bit-symmetric
                d0 += tCent[(d    ) * TPAD + top] * tCent[(d    ) * TPAD + t];
                d1 += tCent[(d + 1) * TPAD + top] * tCent[(d + 1) * TPAD + t];
                d2 += tCent[(d + 2) * TPAD + top] * tCent[(d + 2) * TPAD + t];
                d3 += tCent[(d + 3) * TPAD + top] * tCent[(d + 3) * TPAD + t];
            }
            double dot = (d0 + d1) + (d2 + d3);
            double sb = tSz[top], sm = tSz[t];
            double f = (sb * sm) / (sb + sm);
            Dv = (2.0 * f) * ((tNr[top] + tNr[t]) - 2.0 * dot);
            Pi = t;
        }
        {   // block lexmin -> (sNNv, sNNi)
            double v = Dv; int ix = Pi;
            for (int off = 1; off < 64; off <<= 1) {
                double ov = __shfl_xor(v, off);
                int    oi = __shfl_xor(ix, off);
                if (ov < v || (ov == v && oi < ix)) { v = ov; ix = oi; }
            }
            if (lane == 0) { wRedV[w] = v; wRedI[w] = ix; }
            __syncthreads();
            if (t == 0) {
                double bv = wRedV[0]; int bi = wRedI[0];
                for (int i = 1; i < 8; ++i)
                    if (wRedV[i] < bv || (wRedV[i] == bv && wRedI[i] < bi)) { bv = wRedV[i]; bi = wRedI[i]; }
                sNNv = bv; sNNi = bi;
            }
            __syncthreads();
        }
        const double nnv = sNNv;
        const int    nni = sNNi;

        if (len >= 2 && (nni == chainP[len - 2] || nnv >= chainD[len - 1])) {
            // mutual pair (top, prev): merge. keep = smaller position (= smaller id)
            const int prev = chainP[len - 2];
            const int keep = (top < prev) ? top : prev;
            const int kill = (top < prev) ? prev : top;
            const double sb = tSz[keep], sj = tSz[kill], s2 = sb + sj;
            if (t < 128) {
                if (t < DIM) {
                    double v = (sb * tCent[t * TPAD + keep] + sj * tCent[t * TPAD + kill]) / s2;
                    tCent[t * TPAD + keep] = v;
                    pSq[t] = v * v;
                } else pSq[t] = 0.0;
            }
            __syncthreads();
            if (t < 64) {                              // deterministic nrm reduce
                double s = pSq[t] + pSq[t + 64];
#pragma unroll
                for (int off = 1; off < 64; off <<= 1)
                    s += __shfl_xor(s, off);
                if (t == 0) {
                    tNr[keep] = s;
                    tSz[keep] = s2;
                    tAct[kill] = 0;
                    int r = atomicAdd(&g_mcount, 1);
                    g_reci[r] = tCid[keep]; g_recj[r] = tCid[kill];
                    g_rech[r] = chainD[len - 1] < nnv ? chainD[len - 1] : nnv;
                    sLen = len - 2;
                    sA = aa - 1;
                }
            }
            __syncthreads();
        } else {
            if (t == 0) { chainP[len] = nni; chainD[len] = nnv; sLen = len + 1; }
            __syncthreads();
        }
    }

    // ---- phase C: sort heights, apply n-k smallest, rank roots, scatter ----
    double* fD0 = tCent;                       // overlay: tail data dead now
    int* fI0 = (int*)(tCent + 2048);
    int* fI1 = (int*)(tCent + 3072);
    int* fI2 = (int*)(tCent + 4096);
    int* fI3 = (int*)(tCent + 5120);
    int* fI4 = (int*)(tCent + 6144);

    const int M = g_mcount;
    const int nsel = NPTS - k;
    __syncthreads();
    for (int e = t; e < NPTS; e += FNTHR) {
        fD0[e] = (e < M) ? g_rech[e] : (double)INFINITY;
        fI0[e] = e;
    }
    __syncthreads();
    for (int k2 = 2; k2 <= NPTS; k2 <<= 1) {
        for (int j2 = k2 >> 1; j2 > 0; j2 >>= 1) {
            for (int i = t; i < NPTS; i += FNTHR) {
                int ixj = i ^ j2;
                if (ixj > i) {
                    bool up = ((i & k2) == 0);
                    double a0_ = fD0[i], a1_ = fD0[ixj];
                    if (up ? (a0_ > a1_) : (a0_ < a1_)) {
                        fD0[i] = a1_; fD0[ixj] = a0_;
                        int ti_ = fI0[i]; fI0[i] = fI0[ixj]; fI0[ixj] = ti_;
                    }
                }
            }
            __syncthreads();
        }
    }
    for (int p = t; p < NPTS; p += FNTHR) fI1[p] = p;
    __syncthreads();
    for (int r = t; r < nsel; r += FNTHR) {
        int rec = fI0[r];
        fI1[g_recj[rec]] = g_reci[rec];   // each killed slot appears exactly once
    }
    __syncthreads();
    int* psrc = fI1; int* pdst = fI2;
    for (int it2 = 0; it2 < 11; ++it2) {          // 2^11 >= max chain depth
        for (int p = t; p < NPTS; p += FNTHR) pdst[p] = psrc[psrc[p]];
        __syncthreads();
        int* tp = psrc; psrc = pdst; pdst = tp;
    }
    for (int p = t; p < NPTS; p += FNTHR) fI3[p] = (psrc[p] == p) ? 1 : 0;
    __syncthreads();
    int* rsrc = fI3; int* rdst = fI4;
    for (int off = 1; off < NPTS; off <<= 1) {
        for (int p = t; p < NPTS; p += FNTHR)
            rdst[p] = rsrc[p] + ((p >= off) ? rsrc[p - off] : 0);
        __syncthreads();
        int* tp = rsrc; rsrc = rdst; rdst = tp;
    }
    for (int p = t; p < NPTS; p += FNTHR) {
        int lbl = rsrc[psrc[p]] - 1;              // rank of root, ascending
        out[(size_t)p * k + lbl] = 1.0f;
    }
}

// -------------------------------------------------------------- launch ----
extern "C" void kernel_launch(void* const* d_in, const int* in_sizes, int n_in,
                              void* d_out, int out_size, void* d_ws, size_t ws_size,
                              hipStream_t stream) {
    const float* x    = (const float*)d_in[0];
    const int*   kptr = (const int*)d_in[1];
    float*       out  = (float*)d_out;

    init_kernel<<<8, 256, 0, stream>>>(x, out, out_size);
    for (int r = 0; r < ROUNDS; ++r) {
        nn_pass<<<NPTS / TB, 512, 0, stream>>>();
        merge_pass<<<1, 1024, 0, stream>>>();
    }
    finisher<<<1, FNTHR, 0, stream>>>(kptr, out);
}

// Round 13
// 5966.561 us; speedup vs baseline: 17.5365x; 2.0928x over previous
//
#include <hip/hip_runtime.h>
#include <math.h>

#define NPTS   2048
#define DIM    96
#define PITCH  2048
#define TB     8
#define ROUNDS 22     // ratio ~0.885/round -> a_22 ~ 140 <= TAILSZ
#define TAILSZ 176
#define TPAD   178
#define FNTHR  512

// ---- fixed-slot state: slot index == cluster representative (min point) ----
__device__ double g_cent[DIM * PITCH];   // transposed centroids, in-place updates
__device__ double g_sz[NPTS];
__device__ double g_nrm[NPTS];           // ||mu||^2
__device__ int    g_act[NPTS];
__device__ int    g_cidx[NPTS];          // compacted active slot ids, ascending
__device__ double g_nnv[NPTS];
__device__ int    g_nni[NPTS];           // -1 for killed slots
__device__ int    g_reci[NPTS];          // merge records: keeper (smaller slot)
__device__ int    g_recj[NPTS];          //                killed (larger slot)
__device__ double g_rech[NPTS];          //                Ward height
__device__ int    g_a, g_done, g_mcount;

// ---------------------------------------------------------------- init ----
__global__ void init_kernel(const float* __restrict__ x,
                            float* __restrict__ out, int out_size) {
    int p = blockIdx.x * 256 + threadIdx.x;   // grid 8 x 256
    for (int i = p; i < out_size; i += 2048) out[i] = 0.0f;   // replaces memset
    if (p < NPTS) {
        double nr = 0.0;
        for (int d = 0; d < DIM; ++d) {
            double v = (double)x[p * DIM + d];
            g_cent[d * PITCH + p] = v;
            nr += v * v;
        }
        g_nrm[p] = nr; g_sz[p] = 1.0; g_act[p] = 1; g_cidx[p] = p;
        g_nni[p] = -1; g_nnv[p] = (double)INFINITY;
    }
    if (p == 0) { g_a = NPTS; g_done = 0; g_mcount = 0; }
}

// -------------------------------------------------------------- nn_pass ----
// (verbatim from the R6/R11-passing kernel)
__global__ void __launch_bounds__(512) nn_pass() {
    if (g_done) return;
    const int a = g_a;
    const int tile0 = blockIdx.x * TB;
    if (tile0 >= a) return;
    const int t = threadIdx.x;

    __shared__ int    sIdx[TB];
    __shared__ double sMu[DIM * TB];
    __shared__ double sNb[TB], sSb[TB];
    __shared__ double sRedV[8 * TB];
    __shared__ int    sRedI[8 * TB];

    if (t < TB) {
        int cm   = tile0 + t;
        int orig = (cm < a) ? g_cidx[cm] : -1;
        sIdx[t] = orig;
        sNb[t]  = (orig >= 0) ? g_nrm[orig] : 0.0;
        sSb[t]  = (orig >= 0) ? g_sz[orig]  : 1.0;
    }
    __syncthreads();
    for (int e = t; e < DIM * TB; e += 512) {
        int col = sIdx[e & 7];
        sMu[e] = (col >= 0) ? g_cent[(e >> 3) * PITCH + col] : 0.0;
    }
    __syncthreads();

    int om[4]; bool vld[4];
#pragma unroll
    for (int q = 0; q < 4; ++q) {
        int m  = t + q * 512;
        vld[q] = (m < a);
        om[q]  = g_cidx[vld[q] ? m : (a - 1)];
    }
    double acc[4][TB];
#pragma unroll
    for (int q = 0; q < 4; ++q)
#pragma unroll
        for (int bi = 0; bi < TB; ++bi) acc[q][bi] = 0.0;

    for (int d = 0; d < DIM; ++d) {
        double mu[TB];
#pragma unroll
        for (int bi = 0; bi < TB; ++bi) mu[bi] = sMu[d * TB + bi];
        double x0 = g_cent[d * PITCH + om[0]];
        double x1 = g_cent[d * PITCH + om[1]];
        double x2 = g_cent[d * PITCH + om[2]];
        double x3 = g_cent[d * PITCH + om[3]];
#pragma unroll
        for (int bi = 0; bi < TB; ++bi) {
            acc[0][bi] += mu[bi] * x0;
            acc[1][bi] += mu[bi] * x1;
            acc[2][bi] += mu[bi] * x2;
            acc[3][bi] += mu[bi] * x3;
        }
    }

    double bv[TB]; int bidx[TB];
#pragma unroll
    for (int bi = 0; bi < TB; ++bi) { bv[bi] = (double)INFINITY; bidx[bi] = 0x7FFFFFFF; }
#pragma unroll
    for (int q = 0; q < 4; ++q) {
        if (!vld[q]) continue;
        int    cm = t + q * 512;
        double sm = g_sz[om[q]], nm = g_nrm[om[q]];
#pragma unroll
        for (int bi = 0; bi < TB; ++bi) {
            double f = (sSb[bi] * sm) / (sSb[bi] + sm);
            double D = (2.0 * f) * ((sNb[bi] + nm) - 2.0 * acc[q][bi]);
            if (cm != tile0 + bi && D < bv[bi]) { bv[bi] = D; bidx[bi] = om[q]; }
        }
    }

    const int lane = t & 63, w = t >> 6;
#pragma unroll
    for (int bi = 0; bi < TB; ++bi) {
        double v = bv[bi]; int ix = bidx[bi];
        for (int off = 1; off < 64; off <<= 1) {
            double ov = __shfl_xor(v, off);
            int    oi = __shfl_xor(ix, off);
            if (ov < v || (ov == v && oi < ix)) { v = ov; ix = oi; }
        }
        if (lane == 0) { sRedV[w * TB + bi] = v; sRedI[w * TB + bi] = ix; }
    }
    __syncthreads();
    if (t < TB && tile0 + t < a) {
        double v = sRedV[t]; int ix = sRedI[t];
        for (int w2 = 1; w2 < 8; ++w2) {
            double ov = sRedV[w2 * TB + t]; int oi = sRedI[w2 * TB + t];
            if (ov < v || (ov == v && oi < ix)) { v = ov; ix = oi; }
        }
        g_nnv[sIdx[t]] = v;
        g_nni[sIdx[t]] = ix;
    }
}

// ----------------------------------------------------------- merge_pass ----
// (verbatim R11; stop condition a2 <= TAILSZ)
__global__ void __launch_bounds__(1024) merge_pass() {
    if (g_done) return;
    __shared__ int sWave[16];
    const int t = threadIdx.x, lane = t & 63, w = t >> 6;

    for (int b = t; b < NPTS; b += 1024) {
        int j = g_nni[b];
        if (j > b && j < NPTS && g_nni[j] == b) {   // mutual pair, b = keeper
            int r = atomicAdd(&g_mcount, 1);
            g_reci[r] = b; g_recj[r] = j; g_rech[r] = g_nnv[b];
            double sb = g_sz[b], sj = g_sz[j], s2 = sb + sj;
            double nr = 0.0;
            for (int d = 0; d < DIM; ++d) {
                double v = (sb * g_cent[d * PITCH + b] + sj * g_cent[d * PITCH + j]) / s2;
                g_cent[d * PITCH + b] = v;
                nr += v * v;
            }
            g_sz[b] = s2; g_nrm[b] = nr;
            g_act[j] = 0; g_nni[j] = -1; g_nnv[j] = (double)INFINITY;
        }
    }
    __syncthreads();

    int e0 = 2 * t, e1 = 2 * t + 1;
    int c0 = g_act[e0], c1 = g_act[e1];
    int sum = c0 + c1;
    int v = sum;
    for (int off = 1; off < 64; off <<= 1) {
        int o = __shfl_up(v, off);
        if (lane >= off) v += o;
    }
    if (lane == 63) sWave[w] = v;
    __syncthreads();
    if (t == 0) {
        int run = 0;
        for (int i = 0; i < 16; ++i) { int x = sWave[i]; sWave[i] = run; run += x; }
    }
    __syncthreads();
    int base = sWave[w] + (v - sum);
    if (c0) g_cidx[base]      = e0;
    if (c1) g_cidx[base + c0] = e1;
    if (t == 1023) {
        int a2 = base + sum;
        g_a = a2;
        g_done = (a2 <= TAILSZ) ? 1 : 0;
    }
}

// ------------------------------------------------------------- finisher ----
// A: FAST fallback MNN rounds (fixed-slot coalesced candidates, LDS state).
// B: NN-CHAIN in LDS from a <= 176 to the full dendrogram (R11-proven).
// C: sort heights, cut n-k smallest, union-find, rank roots, scatter.
__global__ void __launch_bounds__(FNTHR) finisher(const int* __restrict__ kptr,
                                                  float* __restrict__ out) {
    __shared__ unsigned short sCidx[NPTS];     //   4 KB
    __shared__ int    sWS[16];
    __shared__ int    sNp;
    __shared__ double tCent[DIM * TPAD];       // 136.7 KB arena (A/B/C overlays)
    __shared__ double tSz[TAILSZ], tNr[TAILSZ];
    __shared__ double chainD[TAILSZ + 2];
    __shared__ int    chainP[TAILSZ + 2];
    __shared__ int    tCid[TAILSZ];
    __shared__ unsigned char tAct[TAILSZ];
    __shared__ double wRedV[8];
    __shared__ int    wRedI[8];
    __shared__ double sNNv;
    __shared__ int    sNNi;
    __shared__ double pSq[128];
    __shared__ int    sLen, sA;
    // phase-A scratch (separate from arena)
    __shared__ double sMu[TB * DIM];           // 6 KB
    __shared__ double sNb[TB], sSb[TB];
    __shared__ int    sIdx[TB];
    __shared__ double sRedV[64];
    __shared__ int    sRedI[64];

    const int t = threadIdx.x, lane = t & 63, w = t >> 6;
    const int k = *kptr;

    // ---- phase-A LDS state (overlaid on the tail arena; copied out before B)
    double*        aNNv = tCent;                         // [2048]
    int*           aNNi = (int*)(tCent + 2048);          // [2048]
    double*        aSz  = tCent + 3072;                  // [2048]
    double*        aNr  = tCent + 5120;                  // [2048]
    unsigned char* aAct = (unsigned char*)(tCent + 7168);// [2048]

    for (int p = t; p < NPTS; p += FNTHR) {
        aSz[p]  = g_sz[p];
        aNr[p]  = g_nrm[p];
        aAct[p] = (unsigned char)g_act[p];
    }
    __syncthreads();

    // per-block compaction from LDS act
    auto compact_lds = [&]() -> int {
        __syncthreads();
        int base = t * 4;
        int c0 = aAct[base], c1 = aAct[base + 1], c2 = aAct[base + 2], c3 = aAct[base + 3];
        int sum = c0 + c1 + c2 + c3;
        int v = sum;
#pragma unroll
        for (int off = 1; off < 64; off <<= 1) {
            int o = __shfl_up(v, off);
            if (lane >= off) v += o;
        }
        if (lane == 63) sWS[w] = v;
        __syncthreads();
        if (t == 0) {
            int run = 0;
#pragma unroll
            for (int i = 0; i < 8; ++i) { int q = sWS[i]; sWS[i] = run; run += q; }
            sWS[8] = run;
        }
        __syncthreads();
        int ex = sWS[w] + (v - sum);
        if (c0) sCidx[ex] = (unsigned short)base;       ex += c0;
        if (c1) sCidx[ex] = (unsigned short)(base + 1); ex += c1;
        if (c2) sCidx[ex] = (unsigned short)(base + 2); ex += c2;
        if (c3) sCidx[ex] = (unsigned short)(base + 3); ex += c3;
        int aa = sWS[8];
        __syncthreads();
        return aa;
    };

    int a = compact_lds();

    // ---- phase A: fast fallback MNN rounds (fixed-slot coalesced candidates)
    for (int guard = 0; guard < 64 && a > TAILSZ; ++guard) {
        for (int tile0 = 0; tile0 < a; tile0 += TB) {
            __syncthreads();
            if (t < TB) {
                int cm   = tile0 + t;
                int orig = (cm < a) ? (int)sCidx[cm] : -1;
                sIdx[t] = orig;
                sNb[t]  = (orig >= 0) ? aNr[orig] : 0.0;
                sSb[t]  = (orig >= 0) ? aSz[orig] : 1.0;
            }
            __syncthreads();
            for (int e = t; e < DIM * TB; e += FNTHR) {
                int col = sIdx[e & 7];
                sMu[e] = (col >= 0) ? g_cent[(e >> 3) * PITCH + col] : 0.0;
            }
            __syncthreads();

            double acc[4][TB];
#pragma unroll
            for (int q = 0; q < 4; ++q)
#pragma unroll
                for (int bi = 0; bi < TB; ++bi) acc[q][bi] = 0.0;

            for (int d = 0; d < DIM; ++d) {
                double mu[TB];
#pragma unroll
                for (int bi = 0; bi < TB; ++bi) mu[bi] = sMu[d * TB + bi];
                double x0 = g_cent[d * PITCH + t];          // coalesced, full width
                double x1 = g_cent[d * PITCH + t + 512];
                double x2 = g_cent[d * PITCH + t + 1024];
                double x3 = g_cent[d * PITCH + t + 1536];
#pragma unroll
                for (int bi = 0; bi < TB; ++bi) {
                    acc[0][bi] += mu[bi] * x0;
                    acc[1][bi] += mu[bi] * x1;
                    acc[2][bi] += mu[bi] * x2;
                    acc[3][bi] += mu[bi] * x3;
                }
            }

            double bv[TB]; int bidx[TB];
#pragma unroll
            for (int bi = 0; bi < TB; ++bi) { bv[bi] = (double)INFINITY; bidx[bi] = 0x7FFFFFFF; }
#pragma unroll
            for (int q = 0; q < 4; ++q) {
                int m  = t + q * FNTHR;
                int am = aAct[m];
                double sm = aSz[m], nm = aNr[m];
#pragma unroll
                for (int bi = 0; bi < TB; ++bi) {
                    int bcol = sIdx[bi];
                    double f = (sSb[bi] * sm) / (sSb[bi] + sm);
                    double D = (2.0 * f) * ((sNb[bi] + nm) - 2.0 * acc[q][bi]);
                    // ascending m within thread + strict < => smallest slot on ties
                    if (am && m != bcol && D < bv[bi]) { bv[bi] = D; bidx[bi] = m; }
                }
            }
#pragma unroll
            for (int bi = 0; bi < TB; ++bi) {
                double v = bv[bi]; int ix = bidx[bi];
                for (int off = 1; off < 64; off <<= 1) {
                    double ov = __shfl_xor(v, off);
                    int    oi = __shfl_xor(ix, off);
                    if (ov < v || (ov == v && oi < ix)) { v = ov; ix = oi; }
                }
                if (lane == 0) { sRedV[w * TB + bi] = v; sRedI[w * TB + bi] = ix; }
            }
            __syncthreads();
            if (t < TB && tile0 + t < a) {
                double v = sRedV[t]; int ix = sRedI[t];
                for (int w2 = 1; w2 < 8; ++w2) {
                    double ov = sRedV[w2 * TB + t]; int oi = sRedI[w2 * TB + t];
                    if (ov < v || (ov == v && oi < ix)) { v = ov; ix = oi; }
                }
                aNNv[sIdx[t]] = v;
                aNNi[sIdx[t]] = ix;
            }
        }
        __syncthreads();
        if (t == 0) sNp = 0;
        __syncthreads();
        for (int b = t; b < NPTS; b += FNTHR) {
            if (!aAct[b]) continue;
            int j = aNNi[b];
            if (j > b && j < NPTS && aNNi[j] == b) {   // mutual pair, b = keeper
                int r = atomicAdd(&g_mcount, 1);
                g_reci[r] = b; g_recj[r] = j; g_rech[r] = aNNv[b];
                double sb = aSz[b], sj = aSz[j], s2 = sb + sj;
                double nr = 0.0;
                for (int d = 0; d < DIM; ++d) {
                    double v = (sb * g_cent[d * PITCH + b] + sj * g_cent[d * PITCH + j]) / s2;
                    g_cent[d * PITCH + b] = v; nr += v * v;
                }
                aSz[b] = s2; aNr[b] = nr; aAct[j] = 0;
                atomicAdd(&sNp, 1);
            }
        }
        __syncthreads();
        a = compact_lds();
    }

    // ---- copy surviving state OUT of the arena, then load tail centroids ----
    const int a0 = a;
    for (int p = t; p < TAILSZ; p += FNTHR) {
        bool vv = (p < a0);
        int orig = vv ? (int)sCidx[p] : 0;
        tSz[p]  = vv ? aSz[orig] : 1.0;
        tNr[p]  = vv ? aNr[orig] : 0.0;
        tCid[p] = orig;
        tAct[p] = vv ? 1 : 0;
    }
    __syncthreads();                            // state out before arena clobber
    for (int p = t; p < TAILSZ; p += FNTHR) {
        int orig = tCid[p];
        bool vv = (p < a0);
        for (int d = 0; d < DIM; ++d)
            tCent[d * TPAD + p] = vv ? g_cent[d * PITCH + orig] : 0.0;
    }
    if (t == 0) { sLen = 0; sA = a0; }
    __syncthreads();

    // ---- phase B: NN-chain (verbatim R11) ----
    for (int guard = 0; guard < 8 * NPTS; ++guard) {
        int aa  = sA;
        int len = sLen;
        if (aa <= 1) break;

        if (len == 0) {
            double v0 = (t < TAILSZ && tAct[t]) ? 0.0 : (double)INFINITY;
            int    i0 = (t < TAILSZ && tAct[t]) ? t : 0x7FFFFFFF;
            {
                double v = v0; int ix = i0;
                for (int off = 1; off < 64; off <<= 1) {
                    double ov = __shfl_xor(v, off);
                    int    oi = __shfl_xor(ix, off);
                    if (ov < v || (ov == v && oi < ix)) { v = ov; ix = oi; }
                }
                if (lane == 0) { wRedV[w] = v; wRedI[w] = ix; }
                __syncthreads();
                if (t == 0) {
                    double bv = wRedV[0]; int bi = wRedI[0];
                    for (int i = 1; i < 8; ++i)
                        if (wRedV[i] < bv || (wRedV[i] == bv && wRedI[i] < bi)) { bv = wRedV[i]; bi = wRedI[i]; }
                    chainP[0] = bi; chainD[0] = (double)INFINITY; sLen = 1;
                }
                __syncthreads();
            }
            len = 1;
        }
        const int top = chainP[len - 1];

        double Dv = (double)INFINITY; int Pi = 0x7FFFFFFF;
        if (t < TAILSZ && tAct[t] && t != top) {
            double d0 = 0.0, d1 = 0.0, d2 = 0.0, d3 = 0.0;
#pragma unroll
            for (int d = 0; d < DIM; d += 4) {        // 4-way split, bit-symmetric
                d0 += tCent[(d    ) * TPAD + top] * tCent[(d    ) * TPAD + t];
                d1 += tCent[(d + 1) * TPAD + top] * tCent[(d + 1) * TPAD + t];
                d2 += tCent[(d + 2) * TPAD + top] * tCent[(d + 2) * TPAD + t];
                d3 += tCent[(d + 3) * TPAD + top] * tCent[(d + 3) * TPAD + t];
            }
            double dot = (d0 + d1) + (d2 + d3);
            double sb = tSz[top], sm = tSz[t];
            double f = (sb * sm) / (sb + sm);
            Dv = (2.0 * f) * ((tNr[top] + tNr[t]) - 2.0 * dot);
            Pi = t;
        }
        {
            double v = Dv; int ix = Pi;
            for (int off = 1; off < 64; off <<= 1) {
                double ov = __shfl_xor(v, off);
                int    oi = __shfl_xor(ix, off);
                if (ov < v || (ov == v && oi < ix)) { v = ov; ix = oi; }
            }
            if (lane == 0) { wRedV[w] = v; wRedI[w] = ix; }
            __syncthreads();
            if (t == 0) {
                double bv = wRedV[0]; int bi = wRedI[0];
                for (int i = 1; i < 8; ++i)
                    if (wRedV[i] < bv || (wRedV[i] == bv && wRedI[i] < bi)) { bv = wRedV[i]; bi = wRedI[i]; }
                sNNv = bv; sNNi = bi;
            }
            __syncthreads();
        }
        const double nnv = sNNv;
        const int    nni = sNNi;

        if (len >= 2 && (nni == chainP[len - 2] || nnv >= chainD[len - 1])) {
            const int prev = chainP[len - 2];
            const int keep = (top < prev) ? top : prev;
            const int kill = (top < prev) ? prev : top;
            const double sb = tSz[keep], sj = tSz[kill], s2 = sb + sj;
            if (t < 128) {
                if (t < DIM) {
                    double v = (sb * tCent[t * TPAD + keep] + sj * tCent[t * TPAD + kill]) / s2;
                    tCent[t * TPAD + keep] = v;
                    pSq[t] = v * v;
                } else pSq[t] = 0.0;
            }
            __syncthreads();
            if (t < 64) {                              // deterministic nrm reduce
                double s = pSq[t] + pSq[t + 64];
#pragma unroll
                for (int off = 1; off < 64; off <<= 1)
                    s += __shfl_xor(s, off);
                if (t == 0) {
                    tNr[keep] = s;
                    tSz[keep] = s2;
                    tAct[kill] = 0;
                    int r = atomicAdd(&g_mcount, 1);
                    g_reci[r] = tCid[keep]; g_recj[r] = tCid[kill];
                    g_rech[r] = chainD[len - 1] < nnv ? chainD[len - 1] : nnv;
                    sLen = len - 2;
                    sA = aa - 1;
                }
            }
            __syncthreads();
        } else {
            if (t == 0) { chainP[len] = nni; chainD[len] = nnv; sLen = len + 1; }
            __syncthreads();
        }
    }

    // ---- phase C: sort heights, apply n-k smallest, rank roots, scatter ----
    double* fD0 = tCent;                       // overlay: tail data dead now
    int* fI0 = (int*)(tCent + 2048);
    int* fI1 = (int*)(tCent + 3072);
    int* fI2 = (int*)(tCent + 4096);
    int* fI3 = (int*)(tCent + 5120);
    int* fI4 = (int*)(tCent + 6144);

    const int M = g_mcount;
    const int nsel = NPTS - k;
    __syncthreads();
    for (int e = t; e < NPTS; e += FNTHR) {
        fD0[e] = (e < M) ? g_rech[e] : (double)INFINITY;
        fI0[e] = e;
    }
    __syncthreads();
    for (int k2 = 2; k2 <= NPTS; k2 <<= 1) {
        for (int j2 = k2 >> 1; j2 > 0; j2 >>= 1) {
            for (int i = t; i < NPTS; i += FNTHR) {
                int ixj = i ^ j2;
                if (ixj > i) {
                    bool up = ((i & k2) == 0);
                    double a0_ = fD0[i], a1_ = fD0[ixj];
                    if (up ? (a0_ > a1_) : (a0_ < a1_)) {
                        fD0[i] = a1_; fD0[ixj] = a0_;
                        int ti_ = fI0[i]; fI0[i] = fI0[ixj]; fI0[ixj] = ti_;
                    }
                }
            }
            __syncthreads();
        }
    }
    for (int p = t; p < NPTS; p += FNTHR) fI1[p] = p;
    __syncthreads();
    for (int r = t; r < nsel; r += FNTHR) {
        int rec = fI0[r];
        fI1[g_recj[rec]] = g_reci[rec];   // each killed slot appears exactly once
    }
    __syncthreads();
    int* psrc = fI1; int* pdst = fI2;
    for (int it2 = 0; it2 < 11; ++it2) {          // 2^11 >= max chain depth
        for (int p = t; p < NPTS; p += FNTHR) pdst[p] = psrc[psrc[p]];
        __syncthreads();
        int* tp = psrc; psrc = pdst; pdst = tp;
    }
    for (int p = t; p < NPTS; p += FNTHR) fI3[p] = (psrc[p] == p) ? 1 : 0;
    __syncthreads();
    int* rsrc = fI3; int* rdst = fI4;
    for (int off = 1; off < NPTS; off <<= 1) {
        for (int p = t; p < NPTS; p += FNTHR)
            rdst[p] = rsrc[p] + ((p >= off) ? rsrc[p - off] : 0);
        __syncthreads();
        int* tp = rsrc; rsrc = rdst; rdst = tp;
    }
    for (int p = t; p < NPTS; p += FNTHR) {
        int lbl = rsrc[psrc[p]] - 1;              // rank of root, ascending
        out[(size_t)p * k + lbl] = 1.0f;
    }
}

// -------------------------------------------------------------- launch ----
extern "C" void kernel_launch(void* const* d_in, const int* in_sizes, int n_in,
                              void* d_out, int out_size, void* d_ws, size_t ws_size,
                              hipStream_t stream) {
    const float* x    = (const float*)d_in[0];
    const int*   kptr = (const int*)d_in[1];
    float*       out  = (float*)d_out;

    init_kernel<<<8, 256, 0, stream>>>(x, out, out_size);
    for (int r = 0; r < ROUNDS; ++r) {
        nn_pass<<<NPTS / TB, 512, 0, stream>>>();
        merge_pass<<<1, 1024, 0, stream>>>();
    }
    finisher<<<1, FNTHR, 0, stream>>>(kptr, out);
}

// Round 14
// 3784.401 us; speedup vs baseline: 27.6484x; 1.5766x over previous
//
#include <hip/hip_runtime.h>
#include <math.h>

#define NPTS   2048
#define DIM    96
#define PITCH  2048
#define TB     8
#define ROUNDS 30     // recalibrated: ratio ~0.922/round -> a_30 ~ 180 <= TAILSZ-ish
#define TAILSZ 176
#define TPAD   178
#define FNTHR  512

// ---- fixed-slot state: slot index == cluster representative (min point) ----
__device__ double g_cent[DIM * PITCH];   // transposed centroids, in-place updates
__device__ double g_sz[NPTS];
__device__ double g_nrm[NPTS];           // ||mu||^2
__device__ int    g_act[NPTS];
__device__ int    g_cidx[NPTS];          // compacted active slot ids, ascending
__device__ double g_nnv[NPTS];
__device__ int    g_nni[NPTS];           // -1 for killed slots
__device__ int    g_reci[NPTS];          // merge records: keeper (smaller slot)
__device__ int    g_recj[NPTS];          //                killed (larger slot)
__device__ double g_rech[NPTS];          //                Ward height
__device__ int    g_a, g_done, g_mcount;

// ---------------------------------------------------------------- init ----
__global__ void init_kernel(const float* __restrict__ x,
                            float* __restrict__ out, int out_size) {
    int p = blockIdx.x * 256 + threadIdx.x;   // grid 8 x 256
    for (int i = p; i < out_size; i += 2048) out[i] = 0.0f;   // replaces memset
    if (p < NPTS) {
        double nr = 0.0;
        for (int d = 0; d < DIM; ++d) {
            double v = (double)x[p * DIM + d];
            g_cent[d * PITCH + p] = v;
            nr += v * v;
        }
        g_nrm[p] = nr; g_sz[p] = 1.0; g_act[p] = 1; g_cidx[p] = p;
        g_nni[p] = -1; g_nnv[p] = (double)INFINITY;
    }
    if (p == 0) { g_a = NPTS; g_done = 0; g_mcount = 0; }
}

// -------------------------------------------------------------- nn_pass ----
// (verbatim from the R6/R11/R13-passing kernel)
__global__ void __launch_bounds__(512) nn_pass() {
    if (g_done) return;
    const int a = g_a;
    const int tile0 = blockIdx.x * TB;
    if (tile0 >= a) return;
    const int t = threadIdx.x;

    __shared__ int    sIdx[TB];
    __shared__ double sMu[DIM * TB];
    __shared__ double sNb[TB], sSb[TB];
    __shared__ double sRedV[8 * TB];
    __shared__ int    sRedI[8 * TB];

    if (t < TB) {
        int cm   = tile0 + t;
        int orig = (cm < a) ? g_cidx[cm] : -1;
        sIdx[t] = orig;
        sNb[t]  = (orig >= 0) ? g_nrm[orig] : 0.0;
        sSb[t]  = (orig >= 0) ? g_sz[orig]  : 1.0;
    }
    __syncthreads();
    for (int e = t; e < DIM * TB; e += 512) {
        int col = sIdx[e & 7];
        sMu[e] = (col >= 0) ? g_cent[(e >> 3) * PITCH + col] : 0.0;
    }
    __syncthreads();

    int om[4]; bool vld[4];
#pragma unroll
    for (int q = 0; q < 4; ++q) {
        int m  = t + q * 512;
        vld[q] = (m < a);
        om[q]  = g_cidx[vld[q] ? m : (a - 1)];
    }
    double acc[4][TB];
#pragma unroll
    for (int q = 0; q < 4; ++q)
#pragma unroll
        for (int bi = 0; bi < TB; ++bi) acc[q][bi] = 0.0;

    for (int d = 0; d < DIM; ++d) {
        double mu[TB];
#pragma unroll
        for (int bi = 0; bi < TB; ++bi) mu[bi] = sMu[d * TB + bi];
        double x0 = g_cent[d * PITCH + om[0]];
        double x1 = g_cent[d * PITCH + om[1]];
        double x2 = g_cent[d * PITCH + om[2]];
        double x3 = g_cent[d * PITCH + om[3]];
#pragma unroll
        for (int bi = 0; bi < TB; ++bi) {
            acc[0][bi] += mu[bi] * x0;
            acc[1][bi] += mu[bi] * x1;
            acc[2][bi] += mu[bi] * x2;
            acc[3][bi] += mu[bi] * x3;
        }
    }

    double bv[TB]; int bidx[TB];
#pragma unroll
    for (int bi = 0; bi < TB; ++bi) { bv[bi] = (double)INFINITY; bidx[bi] = 0x7FFFFFFF; }
#pragma unroll
    for (int q = 0; q < 4; ++q) {
        if (!vld[q]) continue;
        int    cm = t + q * 512;
        double sm = g_sz[om[q]], nm = g_nrm[om[q]];
#pragma unroll
        for (int bi = 0; bi < TB; ++bi) {
            double f = (sSb[bi] * sm) / (sSb[bi] + sm);
            double D = (2.0 * f) * ((sNb[bi] + nm) - 2.0 * acc[q][bi]);
            if (cm != tile0 + bi && D < bv[bi]) { bv[bi] = D; bidx[bi] = om[q]; }
        }
    }

    const int lane = t & 63, w = t >> 6;
#pragma unroll
    for (int bi = 0; bi < TB; ++bi) {
        double v = bv[bi]; int ix = bidx[bi];
        for (int off = 1; off < 64; off <<= 1) {
            double ov = __shfl_xor(v, off);
            int    oi = __shfl_xor(ix, off);
            if (ov < v || (ov == v && oi < ix)) { v = ov; ix = oi; }
        }
        if (lane == 0) { sRedV[w * TB + bi] = v; sRedI[w * TB + bi] = ix; }
    }
    __syncthreads();
    if (t < TB && tile0 + t < a) {
        double v = sRedV[t]; int ix = sRedI[t];
        for (int w2 = 1; w2 < 8; ++w2) {
            double ov = sRedV[w2 * TB + t]; int oi = sRedI[w2 * TB + t];
            if (ov < v || (ov == v && oi < ix)) { v = ov; ix = oi; }
        }
        g_nnv[sIdx[t]] = v;
        g_nni[sIdx[t]] = ix;
    }
}

// ----------------------------------------------------------- merge_pass ----
// (verbatim R13; stop condition a2 <= TAILSZ)
__global__ void __launch_bounds__(1024) merge_pass() {
    if (g_done) return;
    __shared__ int sWave[16];
    const int t = threadIdx.x, lane = t & 63, w = t >> 6;

    for (int b = t; b < NPTS; b += 1024) {
        int j = g_nni[b];
        if (j > b && j < NPTS && g_nni[j] == b) {   // mutual pair, b = keeper
            int r = atomicAdd(&g_mcount, 1);
            g_reci[r] = b; g_recj[r] = j; g_rech[r] = g_nnv[b];
            double sb = g_sz[b], sj = g_sz[j], s2 = sb + sj;
            double nr = 0.0;
            for (int d = 0; d < DIM; ++d) {
                double v = (sb * g_cent[d * PITCH + b] + sj * g_cent[d * PITCH + j]) / s2;
                g_cent[d * PITCH + b] = v;
                nr += v * v;
            }
            g_sz[b] = s2; g_nrm[b] = nr;
            g_act[j] = 0; g_nni[j] = -1; g_nnv[j] = (double)INFINITY;
        }
    }
    __syncthreads();

    int e0 = 2 * t, e1 = 2 * t + 1;
    int c0 = g_act[e0], c1 = g_act[e1];
    int sum = c0 + c1;
    int v = sum;
    for (int off = 1; off < 64; off <<= 1) {
        int o = __shfl_up(v, off);
        if (lane >= off) v += o;
    }
    if (lane == 63) sWave[w] = v;
    __syncthreads();
    if (t == 0) {
        int run = 0;
        for (int i = 0; i < 16; ++i) { int x = sWave[i]; sWave[i] = run; run += x; }
    }
    __syncthreads();
    int base = sWave[w] + (v - sum);
    if (c0) g_cidx[base]      = e0;
    if (c1) g_cidx[base + c0] = e1;
    if (t == 1023) {
        int a2 = base + sum;
        g_a = a2;
        g_done = (a2 <= TAILSZ) ? 1 : 0;
    }
}

// ------------------------------------------------------------- finisher ----
// A: FAST fallback MNN rounds (fixed-slot coalesced candidates, LDS state).
// B: NN-CHAIN in LDS from a <= 176 to the full dendrogram (R11-proven).
// C: sort heights, cut n-k smallest, union-find, rank roots, scatter.
__global__ void __launch_bounds__(FNTHR) finisher(const int* __restrict__ kptr,
                                                  float* __restrict__ out) {
    __shared__ unsigned short sCidx[NPTS];     //   4 KB
    __shared__ int    sWS[16];
    __shared__ int    sNp;
    __shared__ double tCent[DIM * TPAD];       // 136.7 KB arena (A/B/C overlays)
    __shared__ double tSz[TAILSZ], tNr[TAILSZ];
    __shared__ double chainD[TAILSZ + 2];
    __shared__ int    chainP[TAILSZ + 2];
    __shared__ int    tCid[TAILSZ];
    __shared__ unsigned char tAct[TAILSZ];
    __shared__ double wRedV[8];
    __shared__ int    wRedI[8];
    __shared__ double sNNv;
    __shared__ int    sNNi;
    __shared__ double pSq[128];
    __shared__ int    sLen, sA;
    // phase-A scratch (separate from arena)
    __shared__ double sMu[TB * DIM];           // 6 KB
    __shared__ double sNb[TB], sSb[TB];
    __shared__ int    sIdx[TB];
    __shared__ double sRedV[64];
    __shared__ int    sRedI[64];

    const int t = threadIdx.x, lane = t & 63, w = t >> 6;
    const int k = *kptr;

    // ---- phase-A LDS state (overlaid on the tail arena; copied out before B)
    double*        aNNv = tCent;                         // [2048]
    int*           aNNi = (int*)(tCent + 2048);          // [2048]
    double*        aSz  = tCent + 3072;                  // [2048]
    double*        aNr  = tCent + 5120;                  // [2048]
    unsigned char* aAct = (unsigned char*)(tCent + 7168);// [2048]

    for (int p = t; p < NPTS; p += FNTHR) {
        aSz[p]  = g_sz[p];
        aNr[p]  = g_nrm[p];
        aAct[p] = (unsigned char)g_act[p];
    }
    __syncthreads();

    // per-block compaction from LDS act
    auto compact_lds = [&]() -> int {
        __syncthreads();
        int base = t * 4;
        int c0 = aAct[base], c1 = aAct[base + 1], c2 = aAct[base + 2], c3 = aAct[base + 3];
        int sum = c0 + c1 + c2 + c3;
        int v = sum;
#pragma unroll
        for (int off = 1; off < 64; off <<= 1) {
            int o = __shfl_up(v, off);
            if (lane >= off) v += o;
        }
        if (lane == 63) sWS[w] = v;
        __syncthreads();
        if (t == 0) {
            int run = 0;
#pragma unroll
            for (int i = 0; i < 8; ++i) { int q = sWS[i]; sWS[i] = run; run += q; }
            sWS[8] = run;
        }
        __syncthreads();
        int ex = sWS[w] + (v - sum);
        if (c0) sCidx[ex] = (unsigned short)base;       ex += c0;
        if (c1) sCidx[ex] = (unsigned short)(base + 1); ex += c1;
        if (c2) sCidx[ex] = (unsigned short)(base + 2); ex += c2;
        if (c3) sCidx[ex] = (unsigned short)(base + 3); ex += c3;
        int aa = sWS[8];
        __syncthreads();
        return aa;
    };

    int a = compact_lds();

    // ---- phase A: fast fallback MNN rounds (fixed-slot coalesced candidates)
    for (int guard = 0; guard < 64 && a > TAILSZ; ++guard) {
        for (int tile0 = 0; tile0 < a; tile0 += TB) {
            __syncthreads();
            if (t < TB) {
                int cm   = tile0 + t;
                int orig = (cm < a) ? (int)sCidx[cm] : -1;
                sIdx[t] = orig;
                sNb[t]  = (orig >= 0) ? aNr[orig] : 0.0;
                sSb[t]  = (orig >= 0) ? aSz[orig] : 1.0;
            }
            __syncthreads();
            for (int e = t; e < DIM * TB; e += FNTHR) {
                int col = sIdx[e & 7];
                sMu[e] = (col >= 0) ? g_cent[(e >> 3) * PITCH + col] : 0.0;
            }
            __syncthreads();

            double acc[4][TB];
#pragma unroll
            for (int q = 0; q < 4; ++q)
#pragma unroll
                for (int bi = 0; bi < TB; ++bi) acc[q][bi] = 0.0;

            for (int d = 0; d < DIM; ++d) {
                double mu[TB];
#pragma unroll
                for (int bi = 0; bi < TB; ++bi) mu[bi] = sMu[d * TB + bi];
                double x0 = g_cent[d * PITCH + t];          // coalesced, full width
                double x1 = g_cent[d * PITCH + t + 512];
                double x2 = g_cent[d * PITCH + t + 1024];
                double x3 = g_cent[d * PITCH + t + 1536];
#pragma unroll
                for (int bi = 0; bi < TB; ++bi) {
                    acc[0][bi] += mu[bi] * x0;
                    acc[1][bi] += mu[bi] * x1;
                    acc[2][bi] += mu[bi] * x2;
                    acc[3][bi] += mu[bi] * x3;
                }
            }

            double bv[TB]; int bidx[TB];
#pragma unroll
            for (int bi = 0; bi < TB; ++bi) { bv[bi] = (double)INFINITY; bidx[bi] = 0x7FFFFFFF; }
#pragma unroll
            for (int q = 0; q < 4; ++q) {
                int m  = t + q * FNTHR;
                int am = aAct[m];
                double sm = aSz[m], nm = aNr[m];
#pragma unroll
                for (int bi = 0; bi < TB; ++bi) {
                    int bcol = sIdx[bi];
                    double f = (sSb[bi] * sm) / (sSb[bi] + sm);
                    double D = (2.0 * f) * ((sNb[bi] + nm) - 2.0 * acc[q][bi]);
                    // ascending m within thread + strict < => smallest slot on ties
                    if (am && m != bcol && D < bv[bi]) { bv[bi] = D; bidx[bi] = m; }
                }
            }
#pragma unroll
            for (int bi = 0; bi < TB; ++bi) {
                double v = bv[bi]; int ix = bidx[bi];
                for (int off = 1; off < 64; off <<= 1) {
                    double ov = __shfl_xor(v, off);
                    int    oi = __shfl_xor(ix, off);
                    if (ov < v || (ov == v && oi < ix)) { v = ov; ix = oi; }
                }
                if (lane == 0) { sRedV[w * TB + bi] = v; sRedI[w * TB + bi] = ix; }
            }
            __syncthreads();
            if (t < TB && tile0 + t < a) {
                double v = sRedV[t]; int ix = sRedI[t];
                for (int w2 = 1; w2 < 8; ++w2) {
                    double ov = sRedV[w2 * TB + t]; int oi = sRedI[w2 * TB + t];
                    if (ov < v || (ov == v && oi < ix)) { v = ov; ix = oi; }
                }
                aNNv[sIdx[t]] = v;
                aNNi[sIdx[t]] = ix;
            }
        }
        __syncthreads();
        if (t == 0) sNp = 0;
        __syncthreads();
        for (int b = t; b < NPTS; b += FNTHR) {
            if (!aAct[b]) continue;
            int j = aNNi[b];
            if (j > b && j < NPTS && aNNi[j] == b) {   // mutual pair, b = keeper
                int r = atomicAdd(&g_mcount, 1);
                g_reci[r] = b; g_recj[r] = j; g_rech[r] = aNNv[b];
                double sb = aSz[b], sj = aSz[j], s2 = sb + sj;
                double nr = 0.0;
                for (int d = 0; d < DIM; ++d) {
                    double v = (sb * g_cent[d * PITCH + b] + sj * g_cent[d * PITCH + j]) / s2;
                    g_cent[d * PITCH + b] = v; nr += v * v;
                }
                aSz[b] = s2; aNr[b] = nr; aAct[j] = 0;
                atomicAdd(&sNp, 1);
            }
        }
        __syncthreads();
        a = compact_lds();
    }

    // ---- copy surviving state OUT of the arena, then load tail centroids ----
    const int a0 = a;
    for (int p = t; p < TAILSZ; p += FNTHR) {
        bool vv = (p < a0);
        int orig = vv ? (int)sCidx[p] : 0;
        tSz[p]  = vv ? aSz[orig] : 1.0;
        tNr[p]  = vv ? aNr[orig] : 0.0;
        tCid[p] = orig;
        tAct[p] = vv ? 1 : 0;
    }
    __syncthreads();                            // state out before arena clobber
    for (int p = t; p < TAILSZ; p += FNTHR) {
        int orig = tCid[p];
        bool vv = (p < a0);
        for (int d = 0; d < DIM; ++d)
            tCent[d * TPAD + p] = vv ? g_cent[d * PITCH + orig] : 0.0;
    }
    if (t == 0) { sLen = 0; sA = a0; }
    __syncthreads();

    // ---- phase B: NN-chain (verbatim R11/R13) ----
    for (int guard = 0; guard < 8 * NPTS; ++guard) {
        int aa  = sA;
        int len = sLen;
        if (aa <= 1) break;

        if (len == 0) {
            double v0 = (t < TAILSZ && tAct[t]) ? 0.0 : (double)INFINITY;
            int    i0 = (t < TAILSZ && tAct[t]) ? t : 0x7FFFFFFF;
            {
                double v = v0; int ix = i0;
                for (int off = 1; off < 64; off <<= 1) {
                    double ov = __shfl_xor(v, off);
                    int    oi = __shfl_xor(ix, off);
                    if (ov < v || (ov == v && oi < ix)) { v = ov; ix = oi; }
                }
                if (lane == 0) { wRedV[w] = v; wRedI[w] = ix; }
                __syncthreads();
                if (t == 0) {
                    double bv = wRedV[0]; int bi = wRedI[0];
                    for (int i = 1; i < 8; ++i)
                        if (wRedV[i] < bv || (wRedV[i] == bv && wRedI[i] < bi)) { bv = wRedV[i]; bi = wRedI[i]; }
                    chainP[0] = bi; chainD[0] = (double)INFINITY; sLen = 1;
                }
                __syncthreads();
            }
            len = 1;
        }
        const int top = chainP[len - 1];

        double Dv = (double)INFINITY; int Pi = 0x7FFFFFFF;
        if (t < TAILSZ && tAct[t] && t != top) {
            double d0 = 0.0, d1 = 0.0, d2 = 0.0, d3 = 0.0;
#pragma unroll
            for (int d = 0; d < DIM; d += 4) {        // 4-way split, bit-symmetric
                d0 += tCent[(d    ) * TPAD + top] * tCent[(d    ) * TPAD + t];
                d1 += tCent[(d + 1) * TPAD + top] * tCent[(d + 1) * TPAD + t];
                d2 += tCent[(d + 2) * TPAD + top] * tCent[(d + 2) * TPAD + t];
                d3 += tCent[(d + 3) * TPAD + top] * tCent[(d + 3) * TPAD + t];
            }
            double dot = (d0 + d1) + (d2 + d3);
            double sb = tSz[top], sm = tSz[t];
            double f = (sb * sm) / (sb + sm);
            Dv = (2.0 * f) * ((tNr[top] + tNr[t]) - 2.0 * dot);
            Pi = t;
        }
        {
            double v = Dv; int ix = Pi;
            for (int off = 1; off < 64; off <<= 1) {
                double ov = __shfl_xor(v, off);
                int    oi = __shfl_xor(ix, off);
                if (ov < v || (ov == v && oi < ix)) { v = ov; ix = oi; }
            }
            if (lane == 0) { wRedV[w] = v; wRedI[w] = ix; }
            __syncthreads();
            if (t == 0) {
                double bv = wRedV[0]; int bi = wRedI[0];
                for (int i = 1; i < 8; ++i)
                    if (wRedV[i] < bv || (wRedV[i] == bv && wRedI[i] < bi)) { bv = wRedV[i]; bi = wRedI[i]; }
                sNNv = bv; sNNi = bi;
            }
            __syncthreads();
        }
        const double nnv = sNNv;
        const int    nni = sNNi;

        if (len >= 2 && (nni == chainP[len - 2] || nnv >= chainD[len - 1])) {
            const int prev = chainP[len - 2];
            const int keep = (top < prev) ? top : prev;
            const int kill = (top < prev) ? prev : top;
            const double sb = tSz[keep], sj = tSz[kill], s2 = sb + sj;
            if (t < 128) {
                if (t < DIM) {
                    double v = (sb * tCent[t * TPAD + keep] + sj * tCent[t * TPAD + kill]) / s2;
                    tCent[t * TPAD + keep] = v;
                    pSq[t] = v * v;
                } else pSq[t] = 0.0;
            }
            __syncthreads();
            if (t < 64) {                              // deterministic nrm reduce
                double s = pSq[t] + pSq[t + 64];
#pragma unroll
                for (int off = 1; off < 64; off <<= 1)
                    s += __shfl_xor(s, off);
                if (t == 0) {
                    tNr[keep] = s;
                    tSz[keep] = s2;
                    tAct[kill] = 0;
                    int r = atomicAdd(&g_mcount, 1);
                    g_reci[r] = tCid[keep]; g_recj[r] = tCid[kill];
                    g_rech[r] = chainD[len - 1] < nnv ? chainD[len - 1] : nnv;
                    sLen = len - 2;
                    sA = aa - 1;
                }
            }
            __syncthreads();
        } else {
            if (t == 0) { chainP[len] = nni; chainD[len] = nnv; sLen = len + 1; }
            __syncthreads();
        }
    }

    // ---- phase C: sort heights, apply n-k smallest, rank roots, scatter ----
    double* fD0 = tCent;                       // overlay: tail data dead now
    int* fI0 = (int*)(tCent + 2048);
    int* fI1 = (int*)(tCent + 3072);
    int* fI2 = (int*)(tCent + 4096);
    int* fI3 = (int*)(tCent + 5120);
    int* fI4 = (int*)(tCent + 6144);

    const int M = g_mcount;
    const int nsel = NPTS - k;
    __syncthreads();
    for (int e = t; e < NPTS; e += FNTHR) {
        fD0[e] = (e < M) ? g_rech[e] : (double)INFINITY;
        fI0[e] = e;
    }
    __syncthreads();
    for (int k2 = 2; k2 <= NPTS; k2 <<= 1) {
        for (int j2 = k2 >> 1; j2 > 0; j2 >>= 1) {
            for (int i = t; i < NPTS; i += FNTHR) {
                int ixj = i ^ j2;
                if (ixj > i) {
                    bool up = ((i & k2) == 0);
                    double a0_ = fD0[i], a1_ = fD0[ixj];
                    if (up ? (a0_ > a1_) : (a0_ < a1_)) {
                        fD0[i] = a1_; fD0[ixj] = a0_;
                        int ti_ = fI0[i]; fI0[i] = fI0[ixj]; fI0[ixj] = ti_;
                    }
                }
            }
            __syncthreads();
        }
    }
    for (int p = t; p < NPTS; p += FNTHR) fI1[p] = p;
    __syncthreads();
    for (int r = t; r < nsel; r += FNTHR) {
        int rec = fI0[r];
        fI1[g_recj[rec]] = g_reci[rec];   // each killed slot appears exactly once
    }
    __syncthreads();
    int* psrc = fI1; int* pdst = fI2;
    for (int it2 = 0; it2 < 11; ++it2) {          // 2^11 >= max chain depth
        for (int p = t; p < NPTS; p += FNTHR) pdst[p] = psrc[psrc[p]];
        __syncthreads();
        int* tp = psrc; psrc = pdst; pdst = tp;
    }
    for (int p = t; p < NPTS; p += FNTHR) fI3[p] = (psrc[p] == p) ? 1 : 0;
    __syncthreads();
    int* rsrc = fI3; int* rdst = fI4;
    for (int off = 1; off < NPTS; off <<= 1) {
        for (int p = t; p < NPTS; p += FNTHR)
            rdst[p] = rsrc[p] + ((p >= off) ? rsrc[p - off] : 0);
        __syncthreads();
        int* tp = rsrc; rsrc = rdst; rdst = tp;
    }
    for (int p = t; p < NPTS; p += FNTHR) {
        int lbl = rsrc[psrc[p]] - 1;              // rank of root, ascending
        out[(size_t)p * k + lbl] = 1.0f;
    }
}

// -------------------------------------------------------------- launch ----
extern "C" void kernel_launch(void* const* d_in, const int* in_sizes, int n_in,
                              void* d_out, int out_size, void* d_ws, size_t ws_size,
                              hipStream_t stream) {
    const float* x    = (const float*)d_in[0];
    const int*   kptr = (const int*)d_in[1];
    float*       out  = (float*)d_out;

    init_kernel<<<8, 256, 0, stream>>>(x, out, out_size);
    for (int r = 0; r < ROUNDS; ++r) {
        nn_pass<<<NPTS / TB, 512, 0, stream>>>();
        merge_pass<<<1, 1024, 0, stream>>>();
    }
    finisher<<<1, FNTHR, 0, stream>>>(kptr, out);
}